// Round 1
// baseline (5008.483 us; speedup 1.0000x reference)
//
#include <hip/hip_runtime.h>
#include <hip/hip_bf16.h>

#define BM 64
#define BN 64
#define BK 16

// Generic fp32 GEMM: C[M,N] = A[M,K] * B + bias (+res) (+relu)
// transB: B stored [N,K] row-major (access B[n*ldb+k]) else [K,N] (B[k*ldb+n])
// mode 0: normal store C[r*ldc+n] (+res[r*ldres+n]) (+relu)
// mode 1: proj row remap: orow = (r/49)*196 + rowoff + r%49
// mode 2: qkv scatter into q/k/v [B,NH,196,128]; q scaled by qscale
// mode 3: PV scatter: C[((bz/4)*196 + r)*512 + (bz&3)*128 + n]
__global__ __launch_bounds__(256) void gemm_f32(
    const float* __restrict__ A, long long sA, int lda,
    const float* __restrict__ B, long long sB, int ldb, int transB,
    float* __restrict__ C, long long sC, int ldc,
    const float* __restrict__ bias,
    const float* __restrict__ res, int ldres,
    int M, int N, int K,
    int relu, int mode, int rowoff,
    float* q_out, float* k_out, float* v_out, float qscale)
{
    const int bz = blockIdx.z;
    A += (long long)bz * sA;
    B += (long long)bz * sB;
    if (mode == 0) C += (long long)bz * sC;

    const int bm = blockIdx.y * BM;
    const int bn = blockIdx.x * BN;

    __shared__ float As[BK][BM + 1];
    __shared__ float Bs[BK][BN + 1];

    const int tid = threadIdx.x;
    const int tx = tid & 15;
    const int ty = tid >> 4;

    float acc[4][4] = {};

    for (int k0 = 0; k0 < K; k0 += BK) {
        // stage A tile: As[k][m]
        #pragma unroll
        for (int p = 0; p < 4; ++p) {
            int row = p * 16 + ty;
            int kk  = tx;
            int gr = bm + row, gk = k0 + kk;
            As[kk][row] = (gr < M && gk < K) ? A[(long long)gr * lda + gk] : 0.f;
        }
        // stage B tile: Bs[k][n]
        if (!transB) {
            #pragma unroll
            for (int p = 0; p < 4; ++p) {
                int kk = p * 4 + (tid >> 6);
                int n  = tid & 63;
                int gk = k0 + kk, gn = bn + n;
                Bs[kk][n] = (gk < K && gn < N) ? B[(long long)gk * ldb + gn] : 0.f;
            }
        } else {
            #pragma unroll
            for (int p = 0; p < 4; ++p) {
                int n  = p * 16 + ty;
                int kk = tx;
                int gn = bn + n, gk = k0 + kk;
                Bs[kk][n] = (gn < N && gk < K) ? B[(long long)gn * ldb + gk] : 0.f;
            }
        }
        __syncthreads();

        #pragma unroll
        for (int kk = 0; kk < BK; ++kk) {
            float a[4], b[4];
            #pragma unroll
            for (int i = 0; i < 4; ++i) a[i] = As[kk][ty * 4 + i];
            #pragma unroll
            for (int j = 0; j < 4; ++j) b[j] = Bs[kk][tx * 4 + j];
            #pragma unroll
            for (int i = 0; i < 4; ++i)
                #pragma unroll
                for (int j = 0; j < 4; ++j)
                    acc[i][j] += a[i] * b[j];
        }
        __syncthreads();
    }

    #pragma unroll
    for (int i = 0; i < 4; ++i) {
        int r = bm + ty * 4 + i;
        if (r >= M) continue;
        #pragma unroll
        for (int j = 0; j < 4; ++j) {
            int n = bn + tx * 4 + j;
            if (n >= N) continue;
            float v = acc[i][j];
            if (bias) v += bias[n];
            if (mode == 0) {
                if (res) v += res[(long long)r * ldres + n];
                if (relu) v = fmaxf(v, 0.f);
                C[(long long)r * ldc + n] = v;
            } else if (mode == 1) {
                int orow = (r / 49) * 196 + rowoff + (r % 49);
                C[(long long)orow * ldc + n] = v;
            } else if (mode == 2) {
                int which = n >> 9;
                int hh = (n >> 7) & 3;
                int d  = n & 127;
                int b_ = r / 196, l_ = r % 196;
                long long idx = ((long long)(b_ * 4 + hh) * 196 + l_) * 128 + d;
                if (which == 0)      q_out[idx] = v * qscale;
                else if (which == 1) k_out[idx] = v;
                else                 v_out[idx] = v;
            } else { // mode 3
                int bb = bz >> 2, hh = bz & 3;
                C[(long long)(bb * 196 + r) * 512 + hh * 128 + n] = v;
            }
        }
    }
}

// adaptive avg-pool to 7x7, write channels-last P[(b*49+t)*ch + c]
__global__ __launch_bounds__(64) void pool_k(const float* __restrict__ feat,
                                             float* __restrict__ P,
                                             int ch, int s, int f)
{
    int blk = blockIdx.x;          // b*ch + c
    int b = blk / ch, c = blk % ch;
    const float* plane = feat + ((long long)b * ch + c) * s * s;
    __shared__ float buf[49];
    int lane = threadIdx.x;
    if (lane < 49) buf[lane] = 0.f;
    __syncthreads();
    int n = s * s;
    for (int idx = lane; idx < n; idx += 64) {
        int hh = idx / s, ww = idx % s;
        int bucket = (hh / f) * 7 + (ww / f);
        atomicAdd(&buf[bucket], plane[idx]);
    }
    __syncthreads();
    if (lane < 49) {
        float scale = 1.f / (float)(f * f);
        P[((long long)(b * 49 + lane)) * ch + c] = buf[lane] * scale;
    }
}

// LayerNorm over C=512, one wave per row
__global__ __launch_bounds__(64) void ln_k(const float* __restrict__ x,
                                           float* __restrict__ y,
                                           const float* __restrict__ g,
                                           const float* __restrict__ b)
{
    long long row = blockIdx.x;
    const float* xr = x + row * 512;
    float* yr = y + row * 512;
    int lane = threadIdx.x;
    float v[8];
    float s = 0.f, ss = 0.f;
    #pragma unroll
    for (int p = 0; p < 8; ++p) {
        v[p] = xr[lane + p * 64];
        s += v[p];
        ss += v[p] * v[p];
    }
    #pragma unroll
    for (int off = 32; off >= 1; off >>= 1) {
        s  += __shfl_xor(s, off);
        ss += __shfl_xor(ss, off);
    }
    float mean = s * (1.f / 512.f);
    float var  = ss * (1.f / 512.f) - mean * mean;
    float rstd = rsqrtf(var + 1e-5f);
    #pragma unroll
    for (int p = 0; p < 8; ++p) {
        int c = lane + p * 64;
        yr[c] = (v[p] - mean) * rstd * g[c] + b[c];
    }
}

// softmax over keys with relative-position bias computed inline
// grid (196 queries, 256 batch*head), block 64
__global__ __launch_bounds__(64) void softmax_k(float* __restrict__ S,
                                                const float* __restrict__ bt)
{
    int z = blockIdx.y;     // b*4 + h
    int l = blockIdx.x;     // query index
    int lane = threadIdx.x;
    int h = z & 3;
    float* row = S + ((long long)z * 196 + l) * 196;
    int i1 = l / 14, j1 = l % 14;

    float vals[4];
    float mx = -1e30f;
    #pragma unroll
    for (int p = 0; p < 4; ++p) {
        int m = lane + p * 64;
        float v = -1e30f;
        if (m < 196) {
            int i2 = m / 14, j2 = m % 14;
            int idx = (i1 - i2 + 13) * 27 + (j1 - j2 + 13);
            v = row[m] + bt[idx * 4 + h];
        }
        vals[p] = v;
        mx = fmaxf(mx, v);
    }
    #pragma unroll
    for (int off = 32; off >= 1; off >>= 1) mx = fmaxf(mx, __shfl_xor(mx, off));
    float sum = 0.f;
    #pragma unroll
    for (int p = 0; p < 4; ++p) {
        int m = lane + p * 64;
        float e = (m < 196) ? expf(vals[p] - mx) : 0.f;
        vals[p] = e;
        sum += e;
    }
    #pragma unroll
    for (int off = 32; off >= 1; off >>= 1) sum += __shfl_xor(sum, off);
    float inv = 1.f / sum;
    #pragma unroll
    for (int p = 0; p < 4; ++p) {
        int m = lane + p * 64;
        if (m < 196) row[m] = vals[p] * inv;
    }
}

// out[b,c] = mean over 196 tokens
__global__ __launch_bounds__(512) void mean_k(const float* __restrict__ X,
                                              float* __restrict__ out)
{
    int b = blockIdx.x, c = threadIdx.x;
    const float* xp = X + (long long)b * 196 * 512 + c;
    float s = 0.f;
    for (int t = 0; t < 196; ++t) s += xp[t * 512];
    out[b * 512 + c] = s * (1.f / 196.f);
}

extern "C" void kernel_launch(void* const* d_in, const int* in_sizes, int n_in,
                              void* d_out, int out_size, void* d_ws, size_t ws_size,
                              hipStream_t stream)
{
    const float* feat[4]   = {(const float*)d_in[0], (const float*)d_in[1],
                              (const float*)d_in[2], (const float*)d_in[3]};
    const float* proj_w[4] = {(const float*)d_in[4], (const float*)d_in[6],
                              (const float*)d_in[8], (const float*)d_in[10]};
    const float* proj_b[4] = {(const float*)d_in[5], (const float*)d_in[7],
                              (const float*)d_in[9], (const float*)d_in[11]};
    const float* ln1_g = (const float*)d_in[12];
    const float* ln1_b = (const float*)d_in[13];
    const float* qkv_w = (const float*)d_in[14];
    const float* qkv_b = (const float*)d_in[15];
    const float* bias_table = (const float*)d_in[16];
    const float* attn_pw = (const float*)d_in[17];
    const float* attn_pb = (const float*)d_in[18];
    const float* ln2_g = (const float*)d_in[19];
    const float* ln2_b = (const float*)d_in[20];
    const float* mlp_w1 = (const float*)d_in[21];
    const float* mlp_b1 = (const float*)d_in[22];
    const float* mlp_w2 = (const float*)d_in[23];
    const float* mlp_b2 = (const float*)d_in[24];

    float* ws = (float*)d_ws;
    const long long NXT = 64LL * 196 * 512;  // 6,422,528 floats
    float* X  = ws;
    float* XN = X + NXT;
    float* Q  = XN + NXT;
    float* Kb = Q + NXT;
    float* V  = Kb + NXT;
    float* S  = V + NXT;     // 256*196*196 = 9,834,496 floats
    float* H  = Q;           // MLP hidden aliases Q..S (needs 25.7M <= 29.1M floats)
    float* P  = Q;           // pooling scratch aliases Q (max 3136*768 floats)

    const int chans[4] = {96, 192, 384, 768};
    const int szs[4]   = {56, 28, 14, 7};

    // Phase A: pool + proj into X (token-concat layout)
    for (int i = 0; i < 4; ++i) {
        pool_k<<<64 * chans[i], 64, 0, stream>>>(feat[i], P, chans[i], szs[i], szs[i] / 7);
        gemm_f32<<<dim3(8, 49, 1), 256, 0, stream>>>(
            P, 0, chans[i],
            proj_w[i], 0, chans[i], 1,
            X, 0, 512,
            proj_b[i], nullptr, 0,
            3136, 512, chans[i],
            0, 1, 49 * i,
            nullptr, nullptr, nullptr, 0.f);
    }

    // Phase B: transformer layers
    for (int l = 0; l < 2; ++l) {
        ln_k<<<12544, 64, 0, stream>>>(X, XN, ln1_g + l * 512, ln1_b + l * 512);

        // QKV: [12544,512] x [512,1536] -> scatter q/k/v
        gemm_f32<<<dim3(24, 196, 1), 256, 0, stream>>>(
            XN, 0, 512,
            qkv_w + (long long)l * 512 * 1536, 0, 1536, 0,
            nullptr, 0, 0,
            qkv_b + l * 1536, nullptr, 0,
            12544, 1536, 512,
            0, 2, 0,
            Q, Kb, V, 0.08838834764831845f);

        // scores = q @ k^T, batched over 256 (b,h)
        gemm_f32<<<dim3(4, 4, 256), 256, 0, stream>>>(
            Q, 25088, 128,
            Kb, 25088, 128, 1,
            S, 38416, 196,
            nullptr, nullptr, 0,
            196, 196, 128,
            0, 0, 0,
            nullptr, nullptr, nullptr, 0.f);

        softmax_k<<<dim3(196, 256), 64, 0, stream>>>(S, bias_table + (long long)l * 729 * 4);

        // o = S @ v -> head-merged into XN
        gemm_f32<<<dim3(2, 4, 256), 256, 0, stream>>>(
            S, 38416, 196,
            V, 25088, 128, 0,
            XN, 0, 0,
            nullptr, nullptr, 0,
            196, 128, 196,
            0, 3, 0,
            nullptr, nullptr, nullptr, 0.f);

        // attn proj + residual into X
        gemm_f32<<<dim3(8, 196, 1), 256, 0, stream>>>(
            XN, 0, 512,
            attn_pw + (long long)l * 512 * 512, 0, 512, 0,
            X, 0, 512,
            attn_pb + l * 512, X, 512,
            12544, 512, 512,
            0, 0, 0,
            nullptr, nullptr, nullptr, 0.f);

        ln_k<<<12544, 64, 0, stream>>>(X, XN, ln2_g + l * 512, ln2_b + l * 512);

        // MLP1 + relu -> H
        gemm_f32<<<dim3(32, 196, 1), 256, 0, stream>>>(
            XN, 0, 512,
            mlp_w1 + (long long)l * 512 * 2048, 0, 2048, 0,
            H, 0, 2048,
            mlp_b1 + l * 2048, nullptr, 0,
            12544, 2048, 512,
            1, 0, 0,
            nullptr, nullptr, nullptr, 0.f);

        // MLP2 + residual -> X
        gemm_f32<<<dim3(8, 196, 1), 256, 0, stream>>>(
            H, 0, 2048,
            mlp_w2 + (long long)l * 2048 * 512, 0, 512, 0,
            X, 0, 512,
            mlp_b2 + l * 512, X, 512,
            12544, 512, 2048,
            0, 0, 0,
            nullptr, nullptr, nullptr, 0.f);
    }

    // Phase C: token mean
    mean_k<<<64, 512, 0, stream>>>(X, (float*)d_out);
}

// Round 2
// 1393.771 us; speedup vs baseline: 3.5935x; 3.5935x over previous
//
#include <hip/hip_runtime.h>
#include <hip/hip_bf16.h>

typedef __attribute__((ext_vector_type(8))) short short8;
typedef __attribute__((ext_vector_type(4))) float f32x4;

__device__ __forceinline__ unsigned short f2bf(float x) {
    unsigned int u = __builtin_bit_cast(unsigned int, x);
    unsigned int r = (u + 0x7FFFu + ((u >> 16) & 1u)) >> 16;
    return (unsigned short)r;
}

#define BM 128
#define BN 128
#define BKT 32
#define LDP 40   // padded K stride in LDS (bf16 elems): 80B rows -> conflict-free

// MFMA GEMM: C[M,N] = A[M,K] (f32 or bf16) * B[N,K] (bf16, pre-transposed) + epilogue
// mode 0: fp32 store C[r*ldc+n] (+res, +relu)
// mode 1: proj row remap into X: orow=(r/49)*196+rowoff+r%49 (fp32)
// mode 2: qkv scatter -> q_bf/k_bf (bf16 [z][196][128]), v_t (bf16 [z][128][200] transposed)
// mode 3: PV merge -> bf16 C[((z>>2)*196+r)*512 + (z&3)*128 + n]
// mode 4: bf16 store C[r*ldc+n] (+relu)
__global__ __launch_bounds__(256) void gemm_mfma(
    const void* __restrict__ Av, long long sA, int lda, int af32,
    const unsigned short* __restrict__ B, long long sB, int ldb,
    void* __restrict__ Cv, long long sC, int ldc,
    const float* __restrict__ bias,
    const float* __restrict__ res, int ldres,
    int M, int N, int K,
    int relu, int mode, int rowoff,
    unsigned short* q_out, unsigned short* k_out, unsigned short* v_out,
    float qscale)
{
    const int z = blockIdx.z;
    const float* Af = (const float*)Av + (af32 ? z * sA : 0);
    const unsigned short* Ab = (const unsigned short*)Av + (af32 ? 0 : z * sA);
    B += z * sB;

    const int bm = blockIdx.y * BM;
    const int bn = blockIdx.x * BN;

    __shared__ short As[BM][LDP];
    __shared__ short Bs[BN][LDP];

    const int tid  = threadIdx.x;
    const int wid  = tid >> 6;
    const int lane = tid & 63;
    const int wm   = wid >> 1;       // 0..1
    const int wn   = wid & 1;        // 0..1
    const int slot = lane >> 4;      // 0..3 (k-slot)
    const int lcol = lane & 15;

    const int r_ = tid >> 2;         // 0..63 staging row
    const int s_ = tid & 3;          // 0..3 staging k-slot

    f32x4 acc[4][4];
    #pragma unroll
    for (int i = 0; i < 4; ++i)
        #pragma unroll
        for (int j = 0; j < 4; ++j)
            acc[i][j] = (f32x4){0.f, 0.f, 0.f, 0.f};

    for (int k0 = 0; k0 < K; k0 += BKT) {
        // ---- stage A ----
        #pragma unroll
        for (int it = 0; it < 2; ++it) {
            int m = r_ + it * 64;
            int gr = bm + m;
            int k = k0 + s_ * 8;
            short8 pk;
            if (af32) {
                if (gr < M && k + 8 <= K) {
                    const float* p = Af + (long long)gr * lda + k;
                    float4 v0 = *(const float4*)p;
                    float4 v1 = *(const float4*)(p + 4);
                    pk[0] = (short)f2bf(v0.x); pk[1] = (short)f2bf(v0.y);
                    pk[2] = (short)f2bf(v0.z); pk[3] = (short)f2bf(v0.w);
                    pk[4] = (short)f2bf(v1.x); pk[5] = (short)f2bf(v1.y);
                    pk[6] = (short)f2bf(v1.z); pk[7] = (short)f2bf(v1.w);
                } else {
                    #pragma unroll
                    for (int e = 0; e < 8; ++e) {
                        float v = (gr < M && (k + e) < K) ? Af[(long long)gr * lda + k + e] : 0.f;
                        pk[e] = (short)f2bf(v);
                    }
                }
            } else {
                if (gr < M && k + 8 <= K) {
                    pk = *(const short8*)(Ab + (long long)gr * lda + k);
                } else {
                    #pragma unroll
                    for (int e = 0; e < 8; ++e)
                        pk[e] = (gr < M && (k + e) < K) ? (short)Ab[(long long)gr * lda + k + e] : (short)0;
                }
            }
            *(short8*)&As[m][s_ * 8] = pk;
        }
        // ---- stage B (always bf16 [N][K]) ----
        #pragma unroll
        for (int it = 0; it < 2; ++it) {
            int n = r_ + it * 64;
            int gn = bn + n;
            int k = k0 + s_ * 8;
            short8 pk;
            if (gn < N && k + 8 <= K) {
                pk = *(const short8*)(B + (long long)gn * ldb + k);
            } else {
                #pragma unroll
                for (int e = 0; e < 8; ++e)
                    pk[e] = (gn < N && (k + e) < K) ? (short)B[(long long)gn * ldb + k + e] : (short)0;
            }
            *(short8*)&Bs[n][s_ * 8] = pk;
        }
        __syncthreads();

        short8 afr[4], bfr[4];
        #pragma unroll
        for (int mi = 0; mi < 4; ++mi)
            afr[mi] = *(const short8*)&As[wm * 64 + mi * 16 + lcol][slot * 8];
        #pragma unroll
        for (int ni = 0; ni < 4; ++ni)
            bfr[ni] = *(const short8*)&Bs[wn * 64 + ni * 16 + lcol][slot * 8];
        #pragma unroll
        for (int mi = 0; mi < 4; ++mi)
            #pragma unroll
            for (int ni = 0; ni < 4; ++ni)
                acc[mi][ni] = __builtin_amdgcn_mfma_f32_16x16x32_bf16(
                    afr[mi], bfr[ni], acc[mi][ni], 0, 0, 0);
        __syncthreads();
    }

    // ---- epilogue ----
    float* Cf = (float*)Cv + (mode == 0 ? z * sC : 0);
    unsigned short* Cb = (unsigned short*)Cv;

    #pragma unroll
    for (int mi = 0; mi < 4; ++mi) {
        int rbase = bm + wm * 64 + mi * 16 + slot * 4;
        #pragma unroll
        for (int ni = 0; ni < 4; ++ni) {
            int gc = bn + wn * 64 + ni * 16 + lcol;
            if (gc >= N) continue;
            float bv = bias ? bias[gc] : 0.f;
            f32x4 a = acc[mi][ni];
            #pragma unroll
            for (int rr = 0; rr < 4; ++rr) {
                int gr = rbase + rr;
                if (gr >= M) continue;
                float v = a[rr] + bv;
                if (mode == 0) {
                    if (res) v += res[(long long)gr * ldres + gc];
                    if (relu) v = fmaxf(v, 0.f);
                    Cf[(long long)gr * ldc + gc] = v;
                } else if (mode == 1) {
                    int orow = (gr / 49) * 196 + rowoff + (gr % 49);
                    Cf[(long long)orow * ldc + gc] = v;
                } else if (mode == 2) {
                    int which = gc >> 9;
                    int hh = (gc >> 7) & 3;
                    int d  = gc & 127;
                    int b_ = gr / 196, l_ = gr % 196;
                    int zz = b_ * 4 + hh;
                    if (which == 0)
                        q_out[((long long)zz * 196 + l_) * 128 + d] = f2bf(v * qscale);
                    else if (which == 1)
                        k_out[((long long)zz * 196 + l_) * 128 + d] = f2bf(v);
                    else
                        v_out[((long long)zz * 128 + d) * 200 + l_] = f2bf(v);
                } else if (mode == 3) {
                    int bb = z >> 2, hh = z & 3;
                    Cb[((long long)(bb * 196 + gr)) * 512 + hh * 128 + gc] = f2bf(v);
                } else { // mode 4
                    if (relu) v = fmaxf(v, 0.f);
                    Cb[(long long)gr * ldc + gc] = f2bf(v);
                }
            }
        }
    }
}

// transpose+convert W[K][N] f32 -> Wt[N][K] bf16 (K,N multiples of 32)
__global__ __launch_bounds__(256) void wconv_t(const float* __restrict__ W,
                                               unsigned short* __restrict__ Wt,
                                               int K, int N)
{
    __shared__ float t[32][33];
    int tx = threadIdx.x & 31, ty = threadIdx.x >> 5;   // 32 x 8
    int n0 = blockIdx.x * 32, k0 = blockIdx.y * 32;
    #pragma unroll
    for (int j = 0; j < 4; ++j)
        t[ty + j * 8][tx] = W[(long long)(k0 + ty + j * 8) * N + n0 + tx];
    __syncthreads();
    #pragma unroll
    for (int j = 0; j < 4; ++j)
        Wt[(long long)(n0 + ty + j * 8) * K + k0 + tx] = f2bf(t[tx][ty + j * 8]);
}

// elementwise f32 -> bf16
__global__ __launch_bounds__(256) void wcv_k(const float* __restrict__ in,
                                             unsigned short* __restrict__ out, int n)
{
    int i = blockIdx.x * 256 + threadIdx.x;
    if (i < n) out[i] = f2bf(in[i]);
}

// adaptive avg-pool to 7x7, channels-last P[(b*49+t)*ch + c]
__global__ __launch_bounds__(64) void pool_k(const float* __restrict__ feat,
                                             float* __restrict__ P,
                                             int ch, int s, int f)
{
    int blk = blockIdx.x;
    int b = blk / ch, c = blk % ch;
    const float* plane = feat + ((long long)b * ch + c) * s * s;
    __shared__ float buf[49];
    int lane = threadIdx.x;
    if (lane < 49) buf[lane] = 0.f;
    __syncthreads();
    int n = s * s;
    for (int idx = lane; idx < n; idx += 64) {
        int hh = idx / s, ww = idx % s;
        atomicAdd(&buf[(hh / f) * 7 + (ww / f)], plane[idx]);
    }
    __syncthreads();
    if (lane < 49) {
        float scale = 1.f / (float)(f * f);
        P[((long long)(b * 49 + lane)) * ch + c] = buf[lane] * scale;
    }
}

// LayerNorm over C=512, one wave per row
__global__ __launch_bounds__(64) void ln_k(const float* __restrict__ x,
                                           float* __restrict__ y,
                                           const float* __restrict__ g,
                                           const float* __restrict__ b)
{
    long long row = blockIdx.x;
    const float* xr = x + row * 512;
    float* yr = y + row * 512;
    int lane = threadIdx.x;
    float v[8];
    float s = 0.f, ss = 0.f;
    #pragma unroll
    for (int p = 0; p < 8; ++p) {
        v[p] = xr[lane + p * 64];
        s += v[p]; ss += v[p] * v[p];
    }
    #pragma unroll
    for (int off = 32; off >= 1; off >>= 1) {
        s  += __shfl_xor(s, off);
        ss += __shfl_xor(ss, off);
    }
    float mean = s * (1.f / 512.f);
    float var  = ss * (1.f / 512.f) - mean * mean;
    float rstd = rsqrtf(var + 1e-5f);
    #pragma unroll
    for (int p = 0; p < 8; ++p) {
        int c = lane + p * 64;
        yr[c] = (v[p] - mean) * rstd * g[c] + b[c];
    }
}

// softmax over keys + relative bias; reads fp32 S, writes bf16 Sb (ld 200)
__global__ __launch_bounds__(64) void softmax_k(const float* __restrict__ S,
                                                unsigned short* __restrict__ Sb,
                                                const float* __restrict__ bt)
{
    int zz = blockIdx.y;
    int l = blockIdx.x;
    int lane = threadIdx.x;
    int h = zz & 3;
    const float* row = S + ((long long)zz * 196 + l) * 196;
    unsigned short* orow = Sb + ((long long)zz * 196 + l) * 200;
    int i1 = l / 14, j1 = l % 14;

    float vals[4];
    float mx = -1e30f;
    #pragma unroll
    for (int p = 0; p < 4; ++p) {
        int m = lane + p * 64;
        float v = -1e30f;
        if (m < 196) {
            int i2 = m / 14, j2 = m % 14;
            int idx = (i1 - i2 + 13) * 27 + (j1 - j2 + 13);
            v = row[m] + bt[idx * 4 + h];
        }
        vals[p] = v;
        mx = fmaxf(mx, v);
    }
    #pragma unroll
    for (int off = 32; off >= 1; off >>= 1) mx = fmaxf(mx, __shfl_xor(mx, off));
    float sum = 0.f;
    #pragma unroll
    for (int p = 0; p < 4; ++p) {
        int m = lane + p * 64;
        float e = (m < 196) ? expf(vals[p] - mx) : 0.f;
        vals[p] = e; sum += e;
    }
    #pragma unroll
    for (int off = 32; off >= 1; off >>= 1) sum += __shfl_xor(sum, off);
    float inv = 1.f / sum;
    #pragma unroll
    for (int p = 0; p < 4; ++p) {
        int m = lane + p * 64;
        if (m < 196) orow[m] = f2bf(vals[p] * inv);
    }
}

__global__ __launch_bounds__(512) void mean_k(const float* __restrict__ X,
                                              float* __restrict__ out)
{
    int b = blockIdx.x, c = threadIdx.x;
    const float* xp = X + (long long)b * 196 * 512 + c;
    float s = 0.f;
    for (int t = 0; t < 196; ++t) s += xp[t * 512];
    out[b * 512 + c] = s * (1.f / 196.f);
}

extern "C" void kernel_launch(void* const* d_in, const int* in_sizes, int n_in,
                              void* d_out, int out_size, void* d_ws, size_t ws_size,
                              hipStream_t stream)
{
    const float* feat[4]   = {(const float*)d_in[0], (const float*)d_in[1],
                              (const float*)d_in[2], (const float*)d_in[3]};
    const float* proj_w[4] = {(const float*)d_in[4], (const float*)d_in[6],
                              (const float*)d_in[8], (const float*)d_in[10]};
    const float* proj_b[4] = {(const float*)d_in[5], (const float*)d_in[7],
                              (const float*)d_in[9], (const float*)d_in[11]};
    const float* ln1_g = (const float*)d_in[12];
    const float* ln1_b = (const float*)d_in[13];
    const float* qkv_w = (const float*)d_in[14];
    const float* qkv_b = (const float*)d_in[15];
    const float* bias_table = (const float*)d_in[16];
    const float* attn_pw = (const float*)d_in[17];
    const float* attn_pb = (const float*)d_in[18];
    const float* ln2_g = (const float*)d_in[19];
    const float* ln2_b = (const float*)d_in[20];
    const float* mlp_w1 = (const float*)d_in[21];
    const float* mlp_b1 = (const float*)d_in[22];
    const float* mlp_w2 = (const float*)d_in[23];
    const float* mlp_b2 = (const float*)d_in[24];

    const long long NXT = 64LL * 196 * 512;          // 6,422,528

    float* X  = (float*)d_ws;
    float* XN = X + NXT;
    float* S  = XN + NXT;                            // 256*196*196 f32
    float* P  = S;                                   // pool scratch aliases S
    unsigned short* O_bf = (unsigned short*)S;       // PV out aliases S (S dead by then)

    unsigned short* ub   = (unsigned short*)(S + 256LL * 196 * 196);
    unsigned short* q_bf = ub;                       // [256][196][128]
    unsigned short* k_bf = q_bf + NXT;               // [256][196][128]
    unsigned short* v_t  = k_bf + NXT;               // [256][128][200]
    unsigned short* S_bf = v_t + 256LL * 128 * 200;  // [256][196][200]
    unsigned short* H    = q_bf;                     // MLP hidden aliases q..S_bf
    unsigned short* wts  = S_bf + 256LL * 196 * 200;

    unsigned short* qkvw_t = wts;                        // 2 x [1536][512]
    unsigned short* pw_t   = qkvw_t + 2LL * 1536 * 512;  // 2 x [512][512]
    unsigned short* w1_t   = pw_t   + 2LL * 512 * 512;   // 2 x [2048][512]
    unsigned short* w2_t   = w1_t   + 2LL * 2048 * 512;  // 2 x [512][2048]
    unsigned short* pjw    = w2_t   + 2LL * 512 * 2048;  // [512][96+192+384+768]
    unsigned short* pjw_i[4];
    const int chans[4] = {96, 192, 384, 768};
    const int szs[4]   = {56, 28, 14, 7};
    {
        unsigned short* p = pjw;
        for (int i = 0; i < 4; ++i) { pjw_i[i] = p; p += 512LL * chans[i]; }
    }

    // ---- weight conversion (per launch; ~14MB, cheap) ----
    for (int l = 0; l < 2; ++l) {
        wconv_t<<<dim3(1536/32, 512/32), 256, 0, stream>>>(
            qkv_w + (long long)l * 512 * 1536, qkvw_t + (long long)l * 1536 * 512, 512, 1536);
        wconv_t<<<dim3(512/32, 512/32), 256, 0, stream>>>(
            attn_pw + (long long)l * 512 * 512, pw_t + (long long)l * 512 * 512, 512, 512);
        wconv_t<<<dim3(2048/32, 512/32), 256, 0, stream>>>(
            mlp_w1 + (long long)l * 512 * 2048, w1_t + (long long)l * 2048 * 512, 512, 2048);
        wconv_t<<<dim3(512/32, 2048/32), 256, 0, stream>>>(
            mlp_w2 + (long long)l * 2048 * 512, w2_t + (long long)l * 512 * 2048, 2048, 512);
    }
    for (int i = 0; i < 4; ++i) {
        int n = 512 * chans[i];
        wcv_k<<<(n + 255) / 256, 256, 0, stream>>>(proj_w[i], pjw_i[i], n);
    }

    // ---- pool + proj ----
    for (int i = 0; i < 4; ++i) {
        pool_k<<<64 * chans[i], 64, 0, stream>>>(feat[i], P, chans[i], szs[i], szs[i] / 7);
        gemm_mfma<<<dim3(4, 25, 1), 256, 0, stream>>>(
            P, 0, chans[i], 1,
            pjw_i[i], 0, chans[i],
            X, 0, 512,
            proj_b[i], nullptr, 0,
            3136, 512, chans[i],
            0, 1, 49 * i,
            nullptr, nullptr, nullptr, 0.f);
    }

    // ---- transformer layers ----
    for (int l = 0; l < 2; ++l) {
        ln_k<<<12544, 64, 0, stream>>>(X, XN, ln1_g + l * 512, ln1_b + l * 512);

        gemm_mfma<<<dim3(12, 98, 1), 256, 0, stream>>>(
            XN, 0, 512, 1,
            qkvw_t + (long long)l * 1536 * 512, 0, 512,
            nullptr, 0, 0,
            qkv_b + l * 1536, nullptr, 0,
            12544, 1536, 512,
            0, 2, 0,
            q_bf, k_bf, v_t, 0.08838834764831845f);

        gemm_mfma<<<dim3(2, 2, 256), 256, 0, stream>>>(
            q_bf, 196LL * 128, 128, 0,
            k_bf, 196LL * 128, 128,
            S, 196LL * 196, 196,
            nullptr, nullptr, 0,
            196, 196, 128,
            0, 0, 0,
            nullptr, nullptr, nullptr, 0.f);

        softmax_k<<<dim3(196, 256), 64, 0, stream>>>(S, S_bf, bias_table + (long long)l * 729 * 4);

        gemm_mfma<<<dim3(1, 2, 256), 256, 0, stream>>>(
            S_bf, 196LL * 200, 200, 0,
            v_t, 128LL * 200, 200,
            O_bf, 0, 0,
            nullptr, nullptr, 0,
            196, 128, 196,
            0, 3, 0,
            nullptr, nullptr, nullptr, 0.f);

        gemm_mfma<<<dim3(4, 98, 1), 256, 0, stream>>>(
            O_bf, 0, 512, 0,
            pw_t + (long long)l * 512 * 512, 0, 512,
            X, 0, 512,
            attn_pb + l * 512, X, 512,
            12544, 512, 512,
            0, 0, 0,
            nullptr, nullptr, nullptr, 0.f);

        ln_k<<<12544, 64, 0, stream>>>(X, XN, ln2_g + l * 512, ln2_b + l * 512);

        gemm_mfma<<<dim3(16, 98, 1), 256, 0, stream>>>(
            XN, 0, 512, 1,
            w1_t + (long long)l * 2048 * 512, 0, 512,
            H, 0, 2048,
            mlp_b1 + l * 2048, nullptr, 0,
            12544, 2048, 512,
            1, 4, 0,
            nullptr, nullptr, nullptr, 0.f);

        gemm_mfma<<<dim3(4, 98, 1), 256, 0, stream>>>(
            H, 0, 2048, 0,
            w2_t + (long long)l * 512 * 2048, 0, 2048,
            X, 0, 512,
            mlp_b2 + l * 512, X, 512,
            12544, 512, 2048,
            0, 0, 0,
            nullptr, nullptr, nullptr, 0.f);
    }

    mean_k<<<64, 512, 0, stream>>>(X, (float*)d_out);
}

// Round 3
// 1179.705 us; speedup vs baseline: 4.2455x; 1.1815x over previous
//
#include <hip/hip_runtime.h>
#include <hip/hip_bf16.h>

typedef __attribute__((ext_vector_type(8))) short short8;
typedef __attribute__((ext_vector_type(4))) float f32x4;

__device__ __forceinline__ unsigned short f2bf(float x) {
    unsigned int u = __builtin_bit_cast(unsigned int, x);
    unsigned int r = (u + 0x7FFFu + ((u >> 16) & 1u)) >> 16;
    return (unsigned short)r;
}

#define BM 128
#define BN 128
#define BKT 32
#define LDP 40   // padded K stride in LDS (bf16 elems): 80B rows -> conflict-free

// MFMA GEMM: C[M,N] = A[M,K] (f32 or bf16) * B[N,K] (bf16, pre-transposed) + epilogue
// mode 0: fp32 store C[r*ldc+n] (+res, +relu)
// mode 1: proj row remap into X: orow=(r/49)*196+rowoff+r%49 (fp32)
// mode 2: qkv scatter -> q_bf/k_bf (bf16 [z][196][128]), v_t (bf16 [z][128][200] transposed)
// mode 3: PV merge -> bf16 C[((z>>2)*196+r)*512 + (z&3)*128 + n]
// mode 4: bf16 store C[r*ldc+n] (+relu)
__global__ __launch_bounds__(256) void gemm_mfma(
    const void* __restrict__ Av, long long sA, int lda, int af32,
    const unsigned short* __restrict__ B, long long sB, int ldb,
    void* __restrict__ Cv, long long sC, int ldc,
    const float* __restrict__ bias,
    const float* __restrict__ res, int ldres,
    int M, int N, int K,
    int relu, int mode, int rowoff,
    unsigned short* q_out, unsigned short* k_out, unsigned short* v_out,
    float qscale)
{
    const int z = blockIdx.z;
    const float* Af = (const float*)Av + (af32 ? z * sA : 0);
    const unsigned short* Ab = (const unsigned short*)Av + (af32 ? 0 : z * sA);
    B += z * sB;

    const int bm = blockIdx.y * BM;
    const int bn = blockIdx.x * BN;

    __shared__ short As[BM][LDP];
    __shared__ short Bs[BN][LDP];

    const int tid  = threadIdx.x;
    const int wid  = tid >> 6;
    const int lane = tid & 63;
    const int wm   = wid >> 1;
    const int wn   = wid & 1;
    const int slot = lane >> 4;
    const int lcol = lane & 15;

    const int r_ = tid >> 2;
    const int s_ = tid & 3;

    f32x4 acc[4][4];
    #pragma unroll
    for (int i = 0; i < 4; ++i)
        #pragma unroll
        for (int j = 0; j < 4; ++j)
            acc[i][j] = (f32x4){0.f, 0.f, 0.f, 0.f};

    for (int k0 = 0; k0 < K; k0 += BKT) {
        // ---- stage A ----
        #pragma unroll
        for (int it = 0; it < 2; ++it) {
            int m = r_ + it * 64;
            int gr = bm + m;
            int k = k0 + s_ * 8;
            short8 pk;
            if (af32) {
                if (gr < M && k + 8 <= K) {
                    const float* p = Af + (long long)gr * lda + k;
                    float4 v0 = *(const float4*)p;
                    float4 v1 = *(const float4*)(p + 4);
                    pk[0] = (short)f2bf(v0.x); pk[1] = (short)f2bf(v0.y);
                    pk[2] = (short)f2bf(v0.z); pk[3] = (short)f2bf(v0.w);
                    pk[4] = (short)f2bf(v1.x); pk[5] = (short)f2bf(v1.y);
                    pk[6] = (short)f2bf(v1.z); pk[7] = (short)f2bf(v1.w);
                } else {
                    #pragma unroll
                    for (int e = 0; e < 8; ++e) {
                        float v = (gr < M && (k + e) < K) ? Af[(long long)gr * lda + k + e] : 0.f;
                        pk[e] = (short)f2bf(v);
                    }
                }
            } else {
                if (gr < M && k + 8 <= K) {
                    pk = *(const short8*)(Ab + (long long)gr * lda + k);
                } else {
                    #pragma unroll
                    for (int e = 0; e < 8; ++e)
                        pk[e] = (gr < M && (k + e) < K) ? (short)Ab[(long long)gr * lda + k + e] : (short)0;
                }
            }
            *(short8*)&As[m][s_ * 8] = pk;
        }
        // ---- stage B (always bf16 [N][K]) ----
        #pragma unroll
        for (int it = 0; it < 2; ++it) {
            int n = r_ + it * 64;
            int gn = bn + n;
            int k = k0 + s_ * 8;
            short8 pk;
            if (gn < N && k + 8 <= K) {
                pk = *(const short8*)(B + (long long)gn * ldb + k);
            } else {
                #pragma unroll
                for (int e = 0; e < 8; ++e)
                    pk[e] = (gn < N && (k + e) < K) ? (short)B[(long long)gn * ldb + k + e] : (short)0;
            }
            *(short8*)&Bs[n][s_ * 8] = pk;
        }
        __syncthreads();

        short8 afr[4], bfr[4];
        #pragma unroll
        for (int mi = 0; mi < 4; ++mi)
            afr[mi] = *(const short8*)&As[wm * 64 + mi * 16 + lcol][slot * 8];
        #pragma unroll
        for (int ni = 0; ni < 4; ++ni)
            bfr[ni] = *(const short8*)&Bs[wn * 64 + ni * 16 + lcol][slot * 8];
        #pragma unroll
        for (int mi = 0; mi < 4; ++mi)
            #pragma unroll
            for (int ni = 0; ni < 4; ++ni)
                acc[mi][ni] = __builtin_amdgcn_mfma_f32_16x16x32_bf16(
                    afr[mi], bfr[ni], acc[mi][ni], 0, 0, 0);
        __syncthreads();
    }

    // ---- epilogue ----
    float* Cf = (float*)Cv + (mode == 0 ? z * sC : 0);
    unsigned short* Cb = (unsigned short*)Cv;

    #pragma unroll
    for (int mi = 0; mi < 4; ++mi) {
        int rbase = bm + wm * 64 + mi * 16 + slot * 4;
        #pragma unroll
        for (int ni = 0; ni < 4; ++ni) {
            int gc = bn + wn * 64 + ni * 16 + lcol;
            if (gc >= N) continue;
            float bv = bias ? bias[gc] : 0.f;
            f32x4 a = acc[mi][ni];
            #pragma unroll
            for (int rr = 0; rr < 4; ++rr) {
                int gr = rbase + rr;
                if (gr >= M) continue;
                float v = a[rr] + bv;
                if (mode == 0) {
                    if (res) v += res[(long long)gr * ldres + gc];
                    if (relu) v = fmaxf(v, 0.f);
                    Cf[(long long)gr * ldc + gc] = v;
                } else if (mode == 1) {
                    int orow = (gr / 49) * 196 + rowoff + (gr % 49);
                    Cf[(long long)orow * ldc + gc] = v;
                } else if (mode == 2) {
                    int which = gc >> 9;
                    int hh = (gc >> 7) & 3;
                    int d  = gc & 127;
                    int b_ = gr / 196, l_ = gr % 196;
                    int zz = b_ * 4 + hh;
                    if (which == 0)
                        q_out[((long long)zz * 196 + l_) * 128 + d] = f2bf(v * qscale);
                    else if (which == 1)
                        k_out[((long long)zz * 196 + l_) * 128 + d] = f2bf(v);
                    else
                        v_out[((long long)zz * 128 + d) * 200 + l_] = f2bf(v);
                } else if (mode == 3) {
                    int bb = z >> 2, hh = z & 3;
                    Cb[((long long)(bb * 196 + gr)) * 512 + hh * 128 + gc] = f2bf(v);
                } else { // mode 4
                    if (relu) v = fmaxf(v, 0.f);
                    Cb[(long long)gr * ldc + gc] = f2bf(v);
                }
            }
        }
    }
}

// transpose+convert W[K][N] f32 -> Wt[N][K] bf16, layers via blockIdx.z
__global__ __launch_bounds__(256) void wconv_t(const float* __restrict__ W,
                                               unsigned short* __restrict__ Wt,
                                               int K, int N)
{
    W  += (long long)blockIdx.z * K * N;
    Wt += (long long)blockIdx.z * K * N;
    __shared__ float t[32][33];
    int tx = threadIdx.x & 31, ty = threadIdx.x >> 5;
    int n0 = blockIdx.x * 32, k0 = blockIdx.y * 32;
    #pragma unroll
    for (int j = 0; j < 4; ++j)
        t[ty + j * 8][tx] = W[(long long)(k0 + ty + j * 8) * N + n0 + tx];
    __syncthreads();
    #pragma unroll
    for (int j = 0; j < 4; ++j)
        Wt[(long long)(n0 + ty + j * 8) * K + k0 + tx] = f2bf(t[tx][ty + j * 8]);
}

__global__ __launch_bounds__(256) void wcv_k(const float* __restrict__ in,
                                             unsigned short* __restrict__ out, int n)
{
    int i = blockIdx.x * 256 + threadIdx.x;
    if (i < n) out[i] = f2bf(in[i]);
}

// adaptive avg-pool to 7x7: one wave per (b,c); lane<49 owns one output bucket.
// No atomics, vector row loads. P[(b*49+t)*ch + c]
template<int F>
__global__ __launch_bounds__(256) void pool_k(const float* __restrict__ feat,
                                              float* __restrict__ P, int ch)
{
    const int S = 7 * F;
    int wv = blockIdx.x * 4 + (threadIdx.x >> 6);
    int lane = threadIdx.x & 63;
    int b = wv / ch, c = wv % ch;
    if (lane >= 49) return;
    int oh = lane / 7, ow = lane % 7;
    const float* src = feat + ((long long)b * ch + c) * (S * S) + (oh * F) * S + ow * F;
    float acc = 0.f;
    #pragma unroll
    for (int hh = 0; hh < F; ++hh) {
        const float* row = src + hh * S;
        if constexpr (F == 8) {
            float4 a = *(const float4*)row;
            float4 d = *(const float4*)(row + 4);
            acc += a.x + a.y + a.z + a.w + d.x + d.y + d.z + d.w;
        } else if constexpr (F == 4) {
            float4 a = *(const float4*)row;
            acc += a.x + a.y + a.z + a.w;
        } else if constexpr (F == 2) {
            float2 a = *(const float2*)row;
            acc += a.x + a.y;
        } else {
            acc += row[0];
        }
    }
    P[((long long)(b * 49 + lane)) * ch + c] = acc * (1.f / (F * F));
}

// LayerNorm over C=512, one wave per row, 4 rows/block
__global__ __launch_bounds__(256) void ln_k(const float* __restrict__ x,
                                            float* __restrict__ y,
                                            const float* __restrict__ g,
                                            const float* __restrict__ b)
{
    long long row = blockIdx.x * 4 + (threadIdx.x >> 6);
    const float* xr = x + row * 512;
    float* yr = y + row * 512;
    int lane = threadIdx.x & 63;
    float v[8];
    float s = 0.f, ss = 0.f;
    #pragma unroll
    for (int p = 0; p < 8; ++p) {
        v[p] = xr[lane + p * 64];
        s += v[p]; ss += v[p] * v[p];
    }
    #pragma unroll
    for (int off = 32; off >= 1; off >>= 1) {
        s  += __shfl_xor(s, off);
        ss += __shfl_xor(ss, off);
    }
    float mean = s * (1.f / 512.f);
    float var  = ss * (1.f / 512.f) - mean * mean;
    float rstd = rsqrtf(var + 1e-5f);
    #pragma unroll
    for (int p = 0; p < 8; ++p) {
        int c = lane + p * 64;
        yr[c] = (v[p] - mean) * rstd * g[c] + b[c];
    }
}

// softmax over keys + relative bias; fp32 S in, bf16 Sb (ld 200) out.
// one wave per query row, 4 rows/block: grid (49, 256)
__global__ __launch_bounds__(256) void softmax_k(const float* __restrict__ S,
                                                 unsigned short* __restrict__ Sb,
                                                 const float* __restrict__ bt)
{
    int zz = blockIdx.y;
    int l = blockIdx.x * 4 + (threadIdx.x >> 6);
    int lane = threadIdx.x & 63;
    int h = zz & 3;
    const float* row = S + ((long long)zz * 196 + l) * 196;
    unsigned short* orow = Sb + ((long long)zz * 196 + l) * 200;
    int i1 = l / 14, j1 = l % 14;

    float vals[4];
    float mx = -1e30f;
    #pragma unroll
    for (int p = 0; p < 4; ++p) {
        int m = lane + p * 64;
        float v = -1e30f;
        if (m < 196) {
            int i2 = m / 14, j2 = m % 14;
            int idx = (i1 - i2 + 13) * 27 + (j1 - j2 + 13);
            v = row[m] + bt[idx * 4 + h];
        }
        vals[p] = v;
        mx = fmaxf(mx, v);
    }
    #pragma unroll
    for (int off = 32; off >= 1; off >>= 1) mx = fmaxf(mx, __shfl_xor(mx, off));
    float sum = 0.f;
    #pragma unroll
    for (int p = 0; p < 4; ++p) {
        int m = lane + p * 64;
        float e = (m < 196) ? expf(vals[p] - mx) : 0.f;
        vals[p] = e; sum += e;
    }
    #pragma unroll
    for (int off = 32; off >= 1; off >>= 1) sum += __shfl_xor(sum, off);
    float inv = 1.f / sum;
    #pragma unroll
    for (int p = 0; p < 4; ++p) {
        int m = lane + p * 64;
        if (m < 196) orow[m] = f2bf(vals[p] * inv);
    }
}

__global__ __launch_bounds__(512) void mean_k(const float* __restrict__ X,
                                              float* __restrict__ out)
{
    int b = blockIdx.x, c = threadIdx.x;
    const float* xp = X + (long long)b * 196 * 512 + c;
    float s = 0.f;
    for (int t = 0; t < 196; ++t) s += xp[t * 512];
    out[b * 512 + c] = s * (1.f / 196.f);
}

extern "C" void kernel_launch(void* const* d_in, const int* in_sizes, int n_in,
                              void* d_out, int out_size, void* d_ws, size_t ws_size,
                              hipStream_t stream)
{
    const float* feat[4]   = {(const float*)d_in[0], (const float*)d_in[1],
                              (const float*)d_in[2], (const float*)d_in[3]};
    const float* proj_w[4] = {(const float*)d_in[4], (const float*)d_in[6],
                              (const float*)d_in[8], (const float*)d_in[10]};
    const float* proj_b[4] = {(const float*)d_in[5], (const float*)d_in[7],
                              (const float*)d_in[9], (const float*)d_in[11]};
    const float* ln1_g = (const float*)d_in[12];
    const float* ln1_b = (const float*)d_in[13];
    const float* qkv_w = (const float*)d_in[14];
    const float* qkv_b = (const float*)d_in[15];
    const float* bias_table = (const float*)d_in[16];
    const float* attn_pw = (const float*)d_in[17];
    const float* attn_pb = (const float*)d_in[18];
    const float* ln2_g = (const float*)d_in[19];
    const float* ln2_b = (const float*)d_in[20];
    const float* mlp_w1 = (const float*)d_in[21];
    const float* mlp_b1 = (const float*)d_in[22];
    const float* mlp_w2 = (const float*)d_in[23];
    const float* mlp_b2 = (const float*)d_in[24];

    const long long NXT = 64LL * 196 * 512;          // 6,422,528

    float* X  = (float*)d_ws;
    float* XN = X + NXT;
    float* S  = XN + NXT;                            // 256*196*196 f32
    float* P  = S;                                   // pool scratch aliases S
    unsigned short* O_bf = (unsigned short*)S;       // PV out aliases S (S dead by then)

    unsigned short* ub   = (unsigned short*)(S + 256LL * 196 * 196);
    unsigned short* q_bf = ub;                       // [256][196][128]
    unsigned short* k_bf = q_bf + NXT;               // [256][196][128]
    unsigned short* v_t  = k_bf + NXT;               // [256][128][200]
    unsigned short* S_bf = v_t + 256LL * 128 * 200;  // [256][196][200]
    unsigned short* H    = q_bf;                     // MLP hidden aliases q..S_bf
    unsigned short* wts  = S_bf + 256LL * 196 * 200;

    unsigned short* qkvw_t = wts;                        // 2 x [1536][512]
    unsigned short* pw_t   = qkvw_t + 2LL * 1536 * 512;  // 2 x [512][512]
    unsigned short* w1_t   = pw_t   + 2LL * 512 * 512;   // 2 x [2048][512]
    unsigned short* w2_t   = w1_t   + 2LL * 2048 * 512;  // 2 x [512][2048]
    unsigned short* pjw    = w2_t   + 2LL * 512 * 2048;
    unsigned short* pjw_i[4];
    const int chans[4] = {96, 192, 384, 768};
    {
        unsigned short* p = pjw;
        for (int i = 0; i < 4; ++i) { pjw_i[i] = p; p += 512LL * chans[i]; }
    }

    // ---- weight conversion (both layers per launch via blockIdx.z) ----
    wconv_t<<<dim3(1536/32, 512/32, 2), 256, 0, stream>>>(qkv_w, qkvw_t, 512, 1536);
    wconv_t<<<dim3(512/32, 512/32, 2), 256, 0, stream>>>(attn_pw, pw_t, 512, 512);
    wconv_t<<<dim3(2048/32, 512/32, 2), 256, 0, stream>>>(mlp_w1, w1_t, 512, 2048);
    wconv_t<<<dim3(512/32, 2048/32, 2), 256, 0, stream>>>(mlp_w2, w2_t, 2048, 512);
    for (int i = 0; i < 4; ++i) {
        int n = 512 * chans[i];
        wcv_k<<<(n + 255) / 256, 256, 0, stream>>>(proj_w[i], pjw_i[i], n);
    }

    // ---- pool + proj ----
    pool_k<8><<<64 * 96  / 4, 256, 0, stream>>>(feat[0], P, 96);
    gemm_mfma<<<dim3(4, 25, 1), 256, 0, stream>>>(
        P, 0, 96, 1, pjw_i[0], 0, 96, X, 0, 512, proj_b[0], nullptr, 0,
        3136, 512, 96, 0, 1, 0, nullptr, nullptr, nullptr, 0.f);
    pool_k<4><<<64 * 192 / 4, 256, 0, stream>>>(feat[1], P, 192);
    gemm_mfma<<<dim3(4, 25, 1), 256, 0, stream>>>(
        P, 0, 192, 1, pjw_i[1], 0, 192, X, 0, 512, proj_b[1], nullptr, 0,
        3136, 512, 192, 0, 1, 49, nullptr, nullptr, nullptr, 0.f);
    pool_k<2><<<64 * 384 / 4, 256, 0, stream>>>(feat[2], P, 384);
    gemm_mfma<<<dim3(4, 25, 1), 256, 0, stream>>>(
        P, 0, 384, 1, pjw_i[2], 0, 384, X, 0, 512, proj_b[2], nullptr, 0,
        3136, 512, 384, 0, 1, 98, nullptr, nullptr, nullptr, 0.f);
    pool_k<1><<<64 * 768 / 4, 256, 0, stream>>>(feat[3], P, 768);
    gemm_mfma<<<dim3(4, 25, 1), 256, 0, stream>>>(
        P, 0, 768, 1, pjw_i[3], 0, 768, X, 0, 512, proj_b[3], nullptr, 0,
        3136, 512, 768, 0, 1, 147, nullptr, nullptr, nullptr, 0.f);

    // ---- transformer layers ----
    for (int l = 0; l < 2; ++l) {
        ln_k<<<3136, 256, 0, stream>>>(X, XN, ln1_g + l * 512, ln1_b + l * 512);

        gemm_mfma<<<dim3(12, 98, 1), 256, 0, stream>>>(
            XN, 0, 512, 1,
            qkvw_t + (long long)l * 1536 * 512, 0, 512,
            nullptr, 0, 0,
            qkv_b + l * 1536, nullptr, 0,
            12544, 1536, 512,
            0, 2, 0,
            q_bf, k_bf, v_t, 0.08838834764831845f);

        gemm_mfma<<<dim3(2, 2, 256), 256, 0, stream>>>(
            q_bf, 196LL * 128, 128, 0,
            k_bf, 196LL * 128, 128,
            S, 196LL * 196, 196,
            nullptr, nullptr, 0,
            196, 196, 128,
            0, 0, 0,
            nullptr, nullptr, nullptr, 0.f);

        softmax_k<<<dim3(49, 256), 256, 0, stream>>>(S, S_bf, bias_table + (long long)l * 729 * 4);

        gemm_mfma<<<dim3(1, 2, 256), 256, 0, stream>>>(
            S_bf, 196LL * 200, 200, 0,
            v_t, 128LL * 200, 200,
            O_bf, 0, 0,
            nullptr, nullptr, 0,
            196, 128, 196,
            0, 3, 0,
            nullptr, nullptr, nullptr, 0.f);

        gemm_mfma<<<dim3(4, 98, 1), 256, 0, stream>>>(
            O_bf, 0, 512, 0,
            pw_t + (long long)l * 512 * 512, 0, 512,
            X, 0, 512,
            attn_pb + l * 512, X, 512,
            12544, 512, 512,
            0, 0, 0,
            nullptr, nullptr, nullptr, 0.f);

        ln_k<<<3136, 256, 0, stream>>>(X, XN, ln2_g + l * 512, ln2_b + l * 512);

        gemm_mfma<<<dim3(16, 98, 1), 256, 0, stream>>>(
            XN, 0, 512, 1,
            w1_t + (long long)l * 2048 * 512, 0, 512,
            H, 0, 2048,
            mlp_b1 + l * 2048, nullptr, 0,
            12544, 2048, 512,
            1, 4, 0,
            nullptr, nullptr, nullptr, 0.f);

        gemm_mfma<<<dim3(4, 98, 1), 256, 0, stream>>>(
            H, 0, 2048, 0,
            w2_t + (long long)l * 512 * 2048, 0, 2048,
            X, 0, 512,
            mlp_b2 + l * 512, X, 512,
            12544, 512, 2048,
            0, 0, 0,
            nullptr, nullptr, nullptr, 0.f);
    }

    mean_k<<<64, 512, 0, stream>>>(X, (float*)d_out);
}

// Round 5
// 929.597 us; speedup vs baseline: 5.3878x; 1.2690x over previous
//
#include <hip/hip_runtime.h>
#include <hip/hip_bf16.h>

typedef __attribute__((ext_vector_type(8))) short short8;
typedef __attribute__((ext_vector_type(4))) float f32x4;

__device__ __forceinline__ unsigned short f2bf(float x) {
    unsigned int u = __builtin_bit_cast(unsigned int, x);
    unsigned int r = (u + 0x7FFFu + ((u >> 16) & 1u)) >> 16;
    return (unsigned short)r;
}

__device__ __forceinline__ void gload_lds16(const unsigned short* g, unsigned short* l) {
    __builtin_amdgcn_global_load_lds(
        (const __attribute__((address_space(1))) unsigned int*)g,
        (__attribute__((address_space(3))) unsigned int*)l, 16, 0, 0);
}

// MFMA GEMM, all-bf16 operands: C = A[M,K] * B[N,K]^T + epilogue
// A,B bf16 row-major with K contiguous; K % 32 == 0; lda/ldb in elems.
// LDS staged via global_load_lds width=16, linear [128][32] tiles (m97 structure).
// mode 0: fp32 store C[r*ldc+n] (+res fp32, +relu)
// mode 1: proj row remap into X: orow=(r/49)*196+rowoff+r%49 (fp32)
// mode 2: qkv scatter -> q/k bf16 [z][196][128], v_t bf16 [z][128][224]
// mode 3: PV merge -> bf16 C[((z>>2)*196+r)*512 + (z&3)*128 + n]
// mode 4: bf16 store C[r*ldc+n] (+relu)
__global__ __launch_bounds__(256) void gemm_bf16(
    const unsigned short* __restrict__ A, long long sA, int lda,
    const unsigned short* __restrict__ B, long long sB, int ldb,
    void* __restrict__ Cv, long long sC, int ldc,
    const float* __restrict__ bias,
    const float* __restrict__ res, int ldres,
    int M, int N, int K,
    int relu, int mode, int rowoff,
    unsigned short* q_out, unsigned short* k_out, unsigned short* v_out,
    float qscale)
{
    const int z = blockIdx.z;
    A += (long long)z * sA;
    B += (long long)z * sB;

    const int bm = blockIdx.y * 128;
    const int bn = blockIdx.x * 128;

    __shared__ unsigned short As[128][32];
    __shared__ unsigned short Bs[128][32];

    const int tid  = threadIdx.x;
    const int lane = tid & 63;
    const int wid  = tid >> 6;
    const int wm   = wid >> 1;
    const int wn   = wid & 1;
    const int slot = lane >> 4;
    const int lcol = lane & 15;

    const int srow = tid >> 2;        // 0..63
    const int scol = (tid & 3) * 8;   // elem offset 0/8/16/24

    // clamped global row indices for staging (edge tiles read dup rows; epilogue guards)
    int ga0 = bm + srow;       if (ga0 > M - 1) ga0 = M - 1;
    int ga1 = bm + 64 + srow;  if (ga1 > M - 1) ga1 = M - 1;
    int gb0 = bn + srow;       if (gb0 > N - 1) gb0 = N - 1;
    int gb1 = bn + 64 + srow;  if (gb1 > N - 1) gb1 = N - 1;
    const unsigned short* pa0 = A + (long long)ga0 * lda + scol;
    const unsigned short* pa1 = A + (long long)ga1 * lda + scol;
    const unsigned short* pb0 = B + (long long)gb0 * ldb + scol;
    const unsigned short* pb1 = B + (long long)gb1 * ldb + scol;

    f32x4 acc[4][4];
    #pragma unroll
    for (int i = 0; i < 4; ++i)
        #pragma unroll
        for (int j = 0; j < 4; ++j)
            acc[i][j] = (f32x4){0.f, 0.f, 0.f, 0.f};

    for (int k0 = 0; k0 < K; k0 += 32) {
        gload_lds16(pa0 + k0, &As[srow][scol]);
        gload_lds16(pa1 + k0, &As[64 + srow][scol]);
        gload_lds16(pb0 + k0, &Bs[srow][scol]);
        gload_lds16(pb1 + k0, &Bs[64 + srow][scol]);
        __syncthreads();

        short8 afr[4], bfr[4];
        #pragma unroll
        for (int mi = 0; mi < 4; ++mi)
            afr[mi] = *(const short8*)&As[wm * 64 + mi * 16 + lcol][slot * 8];
        #pragma unroll
        for (int ni = 0; ni < 4; ++ni)
            bfr[ni] = *(const short8*)&Bs[wn * 64 + ni * 16 + lcol][slot * 8];
        #pragma unroll
        for (int mi = 0; mi < 4; ++mi)
            #pragma unroll
            for (int ni = 0; ni < 4; ++ni)
                acc[mi][ni] = __builtin_amdgcn_mfma_f32_16x16x32_bf16(
                    afr[mi], bfr[ni], acc[mi][ni], 0, 0, 0);
        __syncthreads();
    }

    // ---- epilogue ----
    float* Cf = (float*)Cv + (mode == 0 ? (long long)z * sC : 0);
    unsigned short* Cb = (unsigned short*)Cv;

    #pragma unroll
    for (int mi = 0; mi < 4; ++mi) {
        int rbase = bm + wm * 64 + mi * 16 + slot * 4;
        #pragma unroll
        for (int ni = 0; ni < 4; ++ni) {
            int gc = bn + wn * 64 + ni * 16 + lcol;
            if (gc >= N) continue;
            float bv = bias ? bias[gc] : 0.f;
            f32x4 a = acc[mi][ni];
            #pragma unroll
            for (int rr = 0; rr < 4; ++rr) {
                int gr = rbase + rr;
                if (gr >= M) continue;
                float v = a[rr] + bv;
                if (mode == 0) {
                    if (res) v += res[(long long)gr * ldres + gc];
                    if (relu) v = fmaxf(v, 0.f);
                    Cf[(long long)gr * ldc + gc] = v;
                } else if (mode == 1) {
                    int orow = (gr / 49) * 196 + rowoff + (gr % 49);
                    Cf[(long long)orow * ldc + gc] = v;
                } else if (mode == 2) {
                    int which = gc >> 9;
                    int hh = (gc >> 7) & 3;
                    int d  = gc & 127;
                    int b_ = gr / 196, l_ = gr % 196;
                    int zz = b_ * 4 + hh;
                    if (which == 0)
                        q_out[((long long)zz * 196 + l_) * 128 + d] = f2bf(v * qscale);
                    else if (which == 1)
                        k_out[((long long)zz * 196 + l_) * 128 + d] = f2bf(v);
                    else
                        v_out[((long long)zz * 128 + d) * 224 + l_] = f2bf(v);
                } else if (mode == 3) {
                    int bb = z >> 2, hh = z & 3;
                    Cb[((long long)(bb * 196 + gr)) * 512 + hh * 128 + gc] = f2bf(v);
                } else { // mode 4
                    if (relu) v = fmaxf(v, 0.f);
                    Cb[(long long)gr * ldc + gc] = f2bf(v);
                }
            }
        }
    }
}

// transpose+convert W[K][N] f32 -> Wt[N][K] bf16, layers via blockIdx.z
__global__ __launch_bounds__(256) void wconv_t(const float* __restrict__ W,
                                               unsigned short* __restrict__ Wt,
                                               int K, int N)
{
    W  += (long long)blockIdx.z * K * N;
    Wt += (long long)blockIdx.z * K * N;
    __shared__ float t[32][33];
    int tx = threadIdx.x & 31, ty = threadIdx.x >> 5;
    int n0 = blockIdx.x * 32, k0 = blockIdx.y * 32;
    #pragma unroll
    for (int j = 0; j < 4; ++j)
        t[ty + j * 8][tx] = W[(long long)(k0 + ty + j * 8) * N + n0 + tx];
    __syncthreads();
    #pragma unroll
    for (int j = 0; j < 4; ++j)
        Wt[(long long)(n0 + ty + j * 8) * K + k0 + tx] = f2bf(t[tx][ty + j * 8]);
}

__global__ __launch_bounds__(256) void wcv_k(const float* __restrict__ in,
                                             unsigned short* __restrict__ out, int n)
{
    int i = blockIdx.x * 256 + threadIdx.x;
    if (i < n) out[i] = f2bf(in[i]);
}

__global__ __launch_bounds__(256) void zero_k(unsigned short* __restrict__ p, long long n8)
{
    long long i = ((long long)blockIdx.x * 256 + threadIdx.x);
    if (i < n8) *(short8*)(p + i * 8) = (short8){0,0,0,0,0,0,0,0};
}

// adaptive avg-pool to 7x7 -> bf16 channels-last P[(b*49+t)*ch + c]
template<int F>
__global__ __launch_bounds__(256) void pool_k(const float* __restrict__ feat,
                                              unsigned short* __restrict__ P, int ch)
{
    const int S = 7 * F;
    int wv = blockIdx.x * 4 + (threadIdx.x >> 6);
    int lane = threadIdx.x & 63;
    int b = wv / ch, c = wv % ch;
    if (lane >= 49) return;
    int oh = lane / 7, ow = lane % 7;
    const float* src = feat + ((long long)b * ch + c) * (S * S) + (oh * F) * S + ow * F;
    float acc = 0.f;
    #pragma unroll
    for (int hh = 0; hh < F; ++hh) {
        const float* row = src + hh * S;
        if constexpr (F == 8) {
            float4 a = *(const float4*)row;
            float4 d = *(const float4*)(row + 4);
            acc += a.x + a.y + a.z + a.w + d.x + d.y + d.z + d.w;
        } else if constexpr (F == 4) {
            float4 a = *(const float4*)row;
            acc += a.x + a.y + a.z + a.w;
        } else if constexpr (F == 2) {
            float2 a = *(const float2*)row;
            acc += a.x + a.y;
        } else {
            acc += row[0];
        }
    }
    P[((long long)(b * 49 + lane)) * ch + c] = f2bf(acc * (1.f / (F * F)));
}

// LayerNorm over C=512 -> bf16 out; one wave per row, 4 rows/block
__global__ __launch_bounds__(256) void ln_k(const float* __restrict__ x,
                                            unsigned short* __restrict__ y,
                                            const float* __restrict__ g,
                                            const float* __restrict__ b)
{
    long long row = blockIdx.x * 4 + (threadIdx.x >> 6);
    const float* xr = x + row * 512;
    unsigned short* yr = y + row * 512;
    int lane = threadIdx.x & 63;
    float v[8];
    float s = 0.f, ss = 0.f;
    #pragma unroll
    for (int p = 0; p < 8; ++p) {
        v[p] = xr[lane + p * 64];
        s += v[p]; ss += v[p] * v[p];
    }
    #pragma unroll
    for (int off = 32; off >= 1; off >>= 1) {
        s  += __shfl_xor(s, off);
        ss += __shfl_xor(ss, off);
    }
    float mean = s * (1.f / 512.f);
    float var  = ss * (1.f / 512.f) - mean * mean;
    float rstd = rsqrtf(var + 1e-5f);
    #pragma unroll
    for (int p = 0; p < 8; ++p) {
        int c = lane + p * 64;
        yr[c] = f2bf((v[p] - mean) * rstd * g[c] + b[c]);
    }
}

// softmax over keys + relative bias; fp32 S in, bf16 Sb (ld 224) out.
__global__ __launch_bounds__(256) void softmax_k(const float* __restrict__ S,
                                                 unsigned short* __restrict__ Sb,
                                                 const float* __restrict__ bt)
{
    int zz = blockIdx.y;
    int l = blockIdx.x * 4 + (threadIdx.x >> 6);
    int lane = threadIdx.x & 63;
    int h = zz & 3;
    const float* row = S + ((long long)zz * 196 + l) * 196;
    unsigned short* orow = Sb + ((long long)zz * 196 + l) * 224;
    int i1 = l / 14, j1 = l % 14;

    float vals[4];
    float mx = -1e30f;
    #pragma unroll
    for (int p = 0; p < 4; ++p) {
        int m = lane + p * 64;
        float v = -1e30f;
        if (m < 196) {
            int i2 = m / 14, j2 = m % 14;
            int idx = (i1 - i2 + 13) * 27 + (j1 - j2 + 13);
            v = row[m] + bt[idx * 4 + h];
        }
        vals[p] = v;
        mx = fmaxf(mx, v);
    }
    #pragma unroll
    for (int off = 32; off >= 1; off >>= 1) mx = fmaxf(mx, __shfl_xor(mx, off));
    float sum = 0.f;
    #pragma unroll
    for (int p = 0; p < 4; ++p) {
        int m = lane + p * 64;
        float e = (m < 196) ? expf(vals[p] - mx) : 0.f;
        vals[p] = e; sum += e;
    }
    #pragma unroll
    for (int off = 32; off >= 1; off >>= 1) sum += __shfl_xor(sum, off);
    float inv = 1.f / sum;
    #pragma unroll
    for (int p = 0; p < 4; ++p) {
        int m = lane + p * 64;
        if (m < 196) orow[m] = f2bf(vals[p] * inv);
    }
}

__global__ __launch_bounds__(512) void mean_k(const float* __restrict__ X,
                                              float* __restrict__ out)
{
    int b = blockIdx.x, c = threadIdx.x;
    const float* xp = X + (long long)b * 196 * 512 + c;
    float s = 0.f;
    for (int t = 0; t < 196; ++t) s += xp[t * 512];
    out[b * 512 + c] = s * (1.f / 196.f);
}

extern "C" void kernel_launch(void* const* d_in, const int* in_sizes, int n_in,
                              void* d_out, int out_size, void* d_ws, size_t ws_size,
                              hipStream_t stream)
{
    const float* feat[4]   = {(const float*)d_in[0], (const float*)d_in[1],
                              (const float*)d_in[2], (const float*)d_in[3]};
    const float* proj_w[4] = {(const float*)d_in[4], (const float*)d_in[6],
                              (const float*)d_in[8], (const float*)d_in[10]};
    const float* proj_b[4] = {(const float*)d_in[5], (const float*)d_in[7],
                              (const float*)d_in[9], (const float*)d_in[11]};
    const float* ln1_g = (const float*)d_in[12];
    const float* ln1_b = (const float*)d_in[13];
    const float* qkv_w = (const float*)d_in[14];
    const float* qkv_b = (const float*)d_in[15];
    const float* bias_table = (const float*)d_in[16];
    const float* attn_pw = (const float*)d_in[17];
    const float* attn_pb = (const float*)d_in[18];
    const float* ln2_g = (const float*)d_in[19];
    const float* ln2_b = (const float*)d_in[20];
    const float* mlp_w1 = (const float*)d_in[21];
    const float* mlp_b1 = (const float*)d_in[22];
    const float* mlp_w2 = (const float*)d_in[23];
    const float* mlp_b2 = (const float*)d_in[24];

    const long long NXT = 64LL * 196 * 512;          // 6,422,528

    float* X  = (float*)d_ws;                        // [12544][512] f32
    float* S  = X + NXT;                             // [256][196][196] f32
    unsigned short* O_bf = (unsigned short*)S;       // PV out aliases S (dead then)

    unsigned short* ub    = (unsigned short*)(S + 256LL * 196 * 196);
    unsigned short* XN_bf = ub;                          // [12544][512]
    unsigned short* q_bf  = XN_bf + NXT;                 // [256][196][128]
    unsigned short* k_bf  = q_bf + NXT;                  // [256][196][128]
    unsigned short* v_t   = k_bf + NXT;                  // [256][128][224]
    unsigned short* S_bf  = v_t + 256LL * 128 * 224;     // [256][196][224]
    unsigned short* H     = q_bf;                        // MLP hidden aliases q..S_bf
    unsigned short* wts   = S_bf + 256LL * 196 * 224;

    unsigned short* qkvw_t = wts;                        // 2 x [1536][512]
    unsigned short* pw_t   = qkvw_t + 2LL * 1536 * 512;  // 2 x [512][512]
    unsigned short* w1_t   = pw_t   + 2LL * 512 * 512;   // 2 x [2048][512]
    unsigned short* w2_t   = w1_t   + 2LL * 2048 * 512;  // 2 x [512][2048]
    unsigned short* pjw    = w2_t   + 2LL * 512 * 2048;
    unsigned short* P_bf   = pjw + 512LL * (96 + 192 + 384 + 768); // [3136][ch]
    unsigned short* pjw_i[4];
    const int chans[4] = {96, 192, 384, 768};
    {
        unsigned short* p = pjw;
        for (int i = 0; i < 4; ++i) { pjw_i[i] = p; p += 512LL * chans[i]; }
    }

    // ---- weight conversion ----
    wconv_t<<<dim3(1536/32, 512/32, 2), 256, 0, stream>>>(qkv_w, qkvw_t, 512, 1536);
    wconv_t<<<dim3(512/32, 512/32, 2), 256, 0, stream>>>(attn_pw, pw_t, 512, 512);
    wconv_t<<<dim3(2048/32, 512/32, 2), 256, 0, stream>>>(mlp_w1, w1_t, 512, 2048);
    wconv_t<<<dim3(512/32, 2048/32, 2), 256, 0, stream>>>(mlp_w2, w2_t, 2048, 512);
    for (int i = 0; i < 4; ++i) {
        int n = 512 * chans[i];
        wcv_k<<<(n + 255) / 256, 256, 0, stream>>>(proj_w[i], pjw_i[i], n);
    }

    // ---- pool + proj ----
    pool_k<8><<<64 * 96  / 4, 256, 0, stream>>>(feat[0], P_bf, 96);
    gemm_bf16<<<dim3(4, 25, 1), 256, 0, stream>>>(
        P_bf, 0, 96, pjw_i[0], 0, 96, X, 0, 512, proj_b[0], nullptr, 0,
        3136, 512, 96, 0, 1, 0, nullptr, nullptr, nullptr, 0.f);
    pool_k<4><<<64 * 192 / 4, 256, 0, stream>>>(feat[1], P_bf, 192);
    gemm_bf16<<<dim3(4, 25, 1), 256, 0, stream>>>(
        P_bf, 0, 192, pjw_i[1], 0, 192, X, 0, 512, proj_b[1], nullptr, 0,
        3136, 512, 192, 0, 1, 49, nullptr, nullptr, nullptr, 0.f);
    pool_k<2><<<64 * 384 / 4, 256, 0, stream>>>(feat[2], P_bf, 384);
    gemm_bf16<<<dim3(4, 25, 1), 256, 0, stream>>>(
        P_bf, 0, 384, pjw_i[2], 0, 384, X, 0, 512, proj_b[2], nullptr, 0,
        3136, 512, 384, 0, 1, 98, nullptr, nullptr, nullptr, 0.f);
    pool_k<1><<<64 * 768 / 4, 256, 0, stream>>>(feat[3], P_bf, 768);
    gemm_bf16<<<dim3(4, 25, 1), 256, 0, stream>>>(
        P_bf, 0, 768, pjw_i[3], 0, 768, X, 0, 512, proj_b[3], nullptr, 0,
        3136, 512, 768, 0, 1, 147, nullptr, nullptr, nullptr, 0.f);

    // ---- transformer layers ----
    for (int l = 0; l < 2; ++l) {
        // re-zero v_t + S_bf pads each layer: MLP hidden H aliases this region,
        // so layer-0's MLP clobbers the K-pad columns layer-1's PV reads.
        {
            long long n8 = (256LL * 224 * (128 + 196)) / 8;
            zero_k<<<(unsigned)((n8 + 255) / 256), 256, 0, stream>>>(v_t, n8);
        }

        ln_k<<<3136, 256, 0, stream>>>(X, XN_bf, ln1_g + l * 512, ln1_b + l * 512);

        gemm_bf16<<<dim3(12, 98, 1), 256, 0, stream>>>(
            XN_bf, 0, 512,
            qkvw_t + (long long)l * 1536 * 512, 0, 512,
            nullptr, 0, 0,
            qkv_b + l * 1536, nullptr, 0,
            12544, 1536, 512,
            0, 2, 0,
            q_bf, k_bf, v_t, 0.08838834764831845f);

        gemm_bf16<<<dim3(2, 2, 256), 256, 0, stream>>>(
            q_bf, 196LL * 128, 128,
            k_bf, 196LL * 128, 128,
            S, 196LL * 196, 196,
            nullptr, nullptr, 0,
            196, 196, 128,
            0, 0, 0,
            nullptr, nullptr, nullptr, 0.f);

        softmax_k<<<dim3(49, 256), 256, 0, stream>>>(S, S_bf, bias_table + (long long)l * 729 * 4);

        gemm_bf16<<<dim3(1, 2, 256), 256, 0, stream>>>(
            S_bf, 196LL * 224, 224,
            v_t, 128LL * 224, 224,
            O_bf, 0, 0,
            nullptr, nullptr, 0,
            196, 128, 224,
            0, 3, 0,
            nullptr, nullptr, nullptr, 0.f);

        gemm_bf16<<<dim3(4, 98, 1), 256, 0, stream>>>(
            O_bf, 0, 512,
            pw_t + (long long)l * 512 * 512, 0, 512,
            X, 0, 512,
            attn_pb + l * 512, X, 512,
            12544, 512, 512,
            0, 0, 0,
            nullptr, nullptr, nullptr, 0.f);

        ln_k<<<3136, 256, 0, stream>>>(X, XN_bf, ln2_g + l * 512, ln2_b + l * 512);

        gemm_bf16<<<dim3(16, 98, 1), 256, 0, stream>>>(
            XN_bf, 0, 512,
            w1_t + (long long)l * 2048 * 512, 0, 512,
            H, 0, 2048,
            mlp_b1 + l * 2048, nullptr, 0,
            12544, 2048, 512,
            1, 4, 0,
            nullptr, nullptr, nullptr, 0.f);

        gemm_bf16<<<dim3(4, 98, 1), 256, 0, stream>>>(
            H, 0, 2048,
            w2_t + (long long)l * 512 * 2048, 0, 2048,
            X, 0, 512,
            mlp_b2 + l * 512, X, 512,
            12544, 512, 2048,
            0, 0, 0,
            nullptr, nullptr, nullptr, 0.f);
    }

    mean_k<<<64, 512, 0, stream>>>(X, (float*)d_out);
}

// Round 6
// 890.484 us; speedup vs baseline: 5.6244x; 1.0439x over previous
//
#include <hip/hip_runtime.h>
#include <hip/hip_bf16.h>

typedef __attribute__((ext_vector_type(8))) short short8;
typedef __attribute__((ext_vector_type(4))) float f32x4;

__device__ __forceinline__ unsigned short f2bf(float x) {
    unsigned int u = __builtin_bit_cast(unsigned int, x);
    unsigned int r = (u + 0x7FFFu + ((u >> 16) & 1u)) >> 16;
    return (unsigned short)r;
}

__device__ __forceinline__ void gload_lds16(const unsigned short* g, unsigned short* l) {
    __builtin_amdgcn_global_load_lds(
        (const __attribute__((address_space(1))) unsigned int*)g,
        (__attribute__((address_space(3))) unsigned int*)l, 16, 0, 0);
}

// MFMA GEMM, all-bf16 operands: C = A[M,K] * B[N,K]^T + epilogue
// A,B bf16 row-major, K contiguous; K % 32 == 0.
// Double-buffered LDS, one-deep prefetch, 1 barrier/k-step.
// XOR swizzle (both-sides involution): LDS dest linear (gload_lds),
// global source col pre-permuted, read offset same XOR -> 2-way banks.
// mode 0: fp32 store C[r*ldc+n] (+res fp32, +relu)
// mode 1: proj row remap into X: orow=(r/49)*196+rowoff+r%49 (fp32)
// mode 2: qkv scatter -> q/k bf16 [z][196][128], v_t bf16 [z][128][224]
// mode 3: PV merge -> bf16 C[((z>>2)*196+r)*512 + (z&3)*128 + n]
// mode 4: bf16 store C[r*ldc+n] (+relu)
__global__ __launch_bounds__(256) void gemm_bf16(
    const unsigned short* __restrict__ A, long long sA, int lda,
    const unsigned short* __restrict__ B, long long sB, int ldb,
    void* __restrict__ Cv, long long sC, int ldc,
    const float* __restrict__ bias,
    const float* __restrict__ res, int ldres,
    int M, int N, int K,
    int relu, int mode, int rowoff,
    unsigned short* q_out, unsigned short* k_out, unsigned short* v_out,
    float qscale)
{
    const int z = blockIdx.z;
    A += (long long)z * sA;
    B += (long long)z * sB;

    const int bm = blockIdx.y * 128;
    const int bn = blockIdx.x * 128;

    __shared__ unsigned short As[2][128][32];
    __shared__ unsigned short Bs[2][128][32];

    const int tid  = threadIdx.x;
    const int lane = tid & 63;
    const int wid  = tid >> 6;
    const int wm   = wid >> 1;
    const int wn   = wid & 1;
    const int slot = lane >> 4;
    const int lcol = lane & 15;

    const int srow = tid >> 2;                         // 0..63 staging row
    const int sgrn = tid & 3;                          // LDS granule (linear)
    const int scol_dst = sgrn * 8;                     // LDS elem offset (linear: tid*16B)
    const int scol_src = (sgrn ^ ((srow >> 1) & 3)) * 8; // swizzled global col

    // read-side swizzled granule: slot' = slot ^ ((row>>1)&3); row base mult of 16
    const int rslot = (slot ^ ((lcol >> 1) & 3)) * 8;

    // clamped global row indices (edge tiles read dup rows; epilogue guards)
    int ga0 = bm + srow;       if (ga0 > M - 1) ga0 = M - 1;
    int ga1 = bm + 64 + srow;  if (ga1 > M - 1) ga1 = M - 1;
    int gb0 = bn + srow;       if (gb0 > N - 1) gb0 = N - 1;
    int gb1 = bn + 64 + srow;  if (gb1 > N - 1) gb1 = N - 1;
    const unsigned short* pa0 = A + (long long)ga0 * lda + scol_src;
    const unsigned short* pa1 = A + (long long)ga1 * lda + scol_src;
    const unsigned short* pb0 = B + (long long)gb0 * ldb + scol_src;
    const unsigned short* pb1 = B + (long long)gb1 * ldb + scol_src;

    f32x4 acc[4][4];
    #pragma unroll
    for (int i = 0; i < 4; ++i)
        #pragma unroll
        for (int j = 0; j < 4; ++j)
            acc[i][j] = (f32x4){0.f, 0.f, 0.f, 0.f};

    const int nt = K >> 5;  // K/32 tiles

    // prologue: stage tile 0 into buf 0
    gload_lds16(pa0, &As[0][srow][scol_dst]);
    gload_lds16(pa1, &As[0][64 + srow][scol_dst]);
    gload_lds16(pb0, &Bs[0][srow][scol_dst]);
    gload_lds16(pb1, &Bs[0][64 + srow][scol_dst]);
    __syncthreads();  // implicit vmcnt(0) drains staging

    for (int t = 0; t < nt; ++t) {
        const int cur = t & 1;
        const int nxt = t + 1;
        if (nxt < nt) {
            const int nb = nxt & 1;
            const int koff = nxt << 5;
            gload_lds16(pa0 + koff, &As[nb][srow][scol_dst]);
            gload_lds16(pa1 + koff, &As[nb][64 + srow][scol_dst]);
            gload_lds16(pb0 + koff, &Bs[nb][srow][scol_dst]);
            gload_lds16(pb1 + koff, &Bs[nb][64 + srow][scol_dst]);
        }

        short8 afr[4], bfr[4];
        #pragma unroll
        for (int mi = 0; mi < 4; ++mi)
            afr[mi] = *(const short8*)&As[cur][wm * 64 + mi * 16 + lcol][rslot];
        #pragma unroll
        for (int ni = 0; ni < 4; ++ni)
            bfr[ni] = *(const short8*)&Bs[cur][wn * 64 + ni * 16 + lcol][rslot];
        #pragma unroll
        for (int mi = 0; mi < 4; ++mi)
            #pragma unroll
            for (int ni = 0; ni < 4; ++ni)
                acc[mi][ni] = __builtin_amdgcn_mfma_f32_16x16x32_bf16(
                    afr[mi], bfr[ni], acc[mi][ni], 0, 0, 0);

        // single barrier per k-step: implicit vmcnt(0) completes the prefetch
        // (issued a full compute-phase ago) and lgkmcnt(0) covers our ds_reads.
        __syncthreads();
    }

    // ---- epilogue ----
    float* Cf = (float*)Cv + (mode == 0 ? (long long)z * sC : 0);
    unsigned short* Cb = (unsigned short*)Cv;

    #pragma unroll
    for (int mi = 0; mi < 4; ++mi) {
        int rbase = bm + wm * 64 + mi * 16 + slot * 4;
        #pragma unroll
        for (int ni = 0; ni < 4; ++ni) {
            int gc = bn + wn * 64 + ni * 16 + lcol;
            if (gc >= N) continue;
            float bv = bias ? bias[gc] : 0.f;
            f32x4 a = acc[mi][ni];
            #pragma unroll
            for (int rr = 0; rr < 4; ++rr) {
                int gr = rbase + rr;
                if (gr >= M) continue;
                float v = a[rr] + bv;
                if (mode == 0) {
                    if (res) v += res[(long long)gr * ldres + gc];
                    if (relu) v = fmaxf(v, 0.f);
                    Cf[(long long)gr * ldc + gc] = v;
                } else if (mode == 1) {
                    int orow = (gr / 49) * 196 + rowoff + (gr % 49);
                    Cf[(long long)orow * ldc + gc] = v;
                } else if (mode == 2) {
                    int which = gc >> 9;
                    int hh = (gc >> 7) & 3;
                    int d  = gc & 127;
                    int b_ = gr / 196, l_ = gr % 196;
                    int zz = b_ * 4 + hh;
                    if (which == 0)
                        q_out[((long long)zz * 196 + l_) * 128 + d] = f2bf(v * qscale);
                    else if (which == 1)
                        k_out[((long long)zz * 196 + l_) * 128 + d] = f2bf(v);
                    else
                        v_out[((long long)zz * 128 + d) * 224 + l_] = f2bf(v);
                } else if (mode == 3) {
                    int bb = z >> 2, hh = z & 3;
                    Cb[((long long)(bb * 196 + gr)) * 512 + hh * 128 + gc] = f2bf(v);
                } else { // mode 4
                    if (relu) v = fmaxf(v, 0.f);
                    Cb[(long long)gr * ldc + gc] = f2bf(v);
                }
            }
        }
    }
}

// transpose+convert W[K][N] f32 -> Wt[N][K] bf16, layers via blockIdx.z
__global__ __launch_bounds__(256) void wconv_t(const float* __restrict__ W,
                                               unsigned short* __restrict__ Wt,
                                               int K, int N)
{
    W  += (long long)blockIdx.z * K * N;
    Wt += (long long)blockIdx.z * K * N;
    __shared__ float t[32][33];
    int tx = threadIdx.x & 31, ty = threadIdx.x >> 5;
    int n0 = blockIdx.x * 32, k0 = blockIdx.y * 32;
    #pragma unroll
    for (int j = 0; j < 4; ++j)
        t[ty + j * 8][tx] = W[(long long)(k0 + ty + j * 8) * N + n0 + tx];
    __syncthreads();
    #pragma unroll
    for (int j = 0; j < 4; ++j)
        Wt[(long long)(n0 + ty + j * 8) * K + k0 + tx] = f2bf(t[tx][ty + j * 8]);
}

__global__ __launch_bounds__(256) void wcv_k(const float* __restrict__ in,
                                             unsigned short* __restrict__ out, int n)
{
    int i = blockIdx.x * 256 + threadIdx.x;
    if (i < n) out[i] = f2bf(in[i]);
}

__global__ __launch_bounds__(256) void zero_k(unsigned short* __restrict__ p, long long n8)
{
    long long i = ((long long)blockIdx.x * 256 + threadIdx.x);
    if (i < n8) *(short8*)(p + i * 8) = (short8){0,0,0,0,0,0,0,0};
}

// adaptive avg-pool to 7x7 -> bf16 channels-last P[(b*49+t)*ch + c]
template<int F>
__global__ __launch_bounds__(256) void pool_k(const float* __restrict__ feat,
                                              unsigned short* __restrict__ P, int ch)
{
    const int S = 7 * F;
    int wv = blockIdx.x * 4 + (threadIdx.x >> 6);
    int lane = threadIdx.x & 63;
    int b = wv / ch, c = wv % ch;
    if (lane >= 49) return;
    int oh = lane / 7, ow = lane % 7;
    const float* src = feat + ((long long)b * ch + c) * (S * S) + (oh * F) * S + ow * F;
    float acc = 0.f;
    #pragma unroll
    for (int hh = 0; hh < F; ++hh) {
        const float* row = src + hh * S;
        if constexpr (F == 8) {
            float4 a = *(const float4*)row;
            float4 d = *(const float4*)(row + 4);
            acc += a.x + a.y + a.z + a.w + d.x + d.y + d.z + d.w;
        } else if constexpr (F == 4) {
            float4 a = *(const float4*)row;
            acc += a.x + a.y + a.z + a.w;
        } else if constexpr (F == 2) {
            float2 a = *(const float2*)row;
            acc += a.x + a.y;
        } else {
            acc += row[0];
        }
    }
    P[((long long)(b * 49 + lane)) * ch + c] = f2bf(acc * (1.f / (F * F)));
}

// LayerNorm over C=512 -> bf16 out; one wave per row, 4 rows/block
__global__ __launch_bounds__(256) void ln_k(const float* __restrict__ x,
                                            unsigned short* __restrict__ y,
                                            const float* __restrict__ g,
                                            const float* __restrict__ b)
{
    long long row = blockIdx.x * 4 + (threadIdx.x >> 6);
    const float* xr = x + row * 512;
    unsigned short* yr = y + row * 512;
    int lane = threadIdx.x & 63;
    float v[8];
    float s = 0.f, ss = 0.f;
    #pragma unroll
    for (int p = 0; p < 8; ++p) {
        v[p] = xr[lane + p * 64];
        s += v[p]; ss += v[p] * v[p];
    }
    #pragma unroll
    for (int off = 32; off >= 1; off >>= 1) {
        s  += __shfl_xor(s, off);
        ss += __shfl_xor(ss, off);
    }
    float mean = s * (1.f / 512.f);
    float var  = ss * (1.f / 512.f) - mean * mean;
    float rstd = rsqrtf(var + 1e-5f);
    #pragma unroll
    for (int p = 0; p < 8; ++p) {
        int c = lane + p * 64;
        yr[c] = f2bf((v[p] - mean) * rstd * g[c] + b[c]);
    }
}

// softmax over keys + relative bias; fp32 S in, bf16 Sb (ld 224) out.
__global__ __launch_bounds__(256) void softmax_k(const float* __restrict__ S,
                                                 unsigned short* __restrict__ Sb,
                                                 const float* __restrict__ bt)
{
    int zz = blockIdx.y;
    int l = blockIdx.x * 4 + (threadIdx.x >> 6);
    int lane = threadIdx.x & 63;
    int h = zz & 3;
    const float* row = S + ((long long)zz * 196 + l) * 196;
    unsigned short* orow = Sb + ((long long)zz * 196 + l) * 224;
    int i1 = l / 14, j1 = l % 14;

    float vals[4];
    float mx = -1e30f;
    #pragma unroll
    for (int p = 0; p < 4; ++p) {
        int m = lane + p * 64;
        float v = -1e30f;
        if (m < 196) {
            int i2 = m / 14, j2 = m % 14;
            int idx = (i1 - i2 + 13) * 27 + (j1 - j2 + 13);
            v = row[m] + bt[idx * 4 + h];
        }
        vals[p] = v;
        mx = fmaxf(mx, v);
    }
    #pragma unroll
    for (int off = 32; off >= 1; off >>= 1) mx = fmaxf(mx, __shfl_xor(mx, off));
    float sum = 0.f;
    #pragma unroll
    for (int p = 0; p < 4; ++p) {
        int m = lane + p * 64;
        float e = (m < 196) ? expf(vals[p] - mx) : 0.f;
        vals[p] = e; sum += e;
    }
    #pragma unroll
    for (int off = 32; off >= 1; off >>= 1) sum += __shfl_xor(sum, off);
    float inv = 1.f / sum;
    #pragma unroll
    for (int p = 0; p < 4; ++p) {
        int m = lane + p * 64;
        if (m < 196) orow[m] = f2bf(vals[p] * inv);
    }
}

__global__ __launch_bounds__(512) void mean_k(const float* __restrict__ X,
                                              float* __restrict__ out)
{
    int b = blockIdx.x, c = threadIdx.x;
    const float* xp = X + (long long)b * 196 * 512 + c;
    float s = 0.f;
    for (int t = 0; t < 196; ++t) s += xp[t * 512];
    out[b * 512 + c] = s * (1.f / 196.f);
}

extern "C" void kernel_launch(void* const* d_in, const int* in_sizes, int n_in,
                              void* d_out, int out_size, void* d_ws, size_t ws_size,
                              hipStream_t stream)
{
    const float* feat[4]   = {(const float*)d_in[0], (const float*)d_in[1],
                              (const float*)d_in[2], (const float*)d_in[3]};
    const float* proj_w[4] = {(const float*)d_in[4], (const float*)d_in[6],
                              (const float*)d_in[8], (const float*)d_in[10]};
    const float* proj_b[4] = {(const float*)d_in[5], (const float*)d_in[7],
                              (const float*)d_in[9], (const float*)d_in[11]};
    const float* ln1_g = (const float*)d_in[12];
    const float* ln1_b = (const float*)d_in[13];
    const float* qkv_w = (const float*)d_in[14];
    const float* qkv_b = (const float*)d_in[15];
    const float* bias_table = (const float*)d_in[16];
    const float* attn_pw = (const float*)d_in[17];
    const float* attn_pb = (const float*)d_in[18];
    const float* ln2_g = (const float*)d_in[19];
    const float* ln2_b = (const float*)d_in[20];
    const float* mlp_w1 = (const float*)d_in[21];
    const float* mlp_b1 = (const float*)d_in[22];
    const float* mlp_w2 = (const float*)d_in[23];
    const float* mlp_b2 = (const float*)d_in[24];

    const long long NXT = 64LL * 196 * 512;          // 6,422,528

    float* X  = (float*)d_ws;                        // [12544][512] f32
    float* S  = X + NXT;                             // [256][196][196] f32
    unsigned short* O_bf = (unsigned short*)S;       // PV out aliases S (dead then)

    unsigned short* ub    = (unsigned short*)(S + 256LL * 196 * 196);
    unsigned short* XN_bf = ub;                          // [12544][512]
    unsigned short* q_bf  = XN_bf + NXT;                 // [256][196][128]
    unsigned short* k_bf  = q_bf + NXT;                  // [256][196][128]
    unsigned short* v_t   = k_bf + NXT;                  // [256][128][224]
    unsigned short* S_bf  = v_t + 256LL * 128 * 224;     // [256][196][224]
    unsigned short* H     = q_bf;                        // MLP hidden aliases q..S_bf
    unsigned short* wts   = S_bf + 256LL * 196 * 224;

    unsigned short* qkvw_t = wts;                        // 2 x [1536][512]
    unsigned short* pw_t   = qkvw_t + 2LL * 1536 * 512;  // 2 x [512][512]
    unsigned short* w1_t   = pw_t   + 2LL * 512 * 512;   // 2 x [2048][512]
    unsigned short* w2_t   = w1_t   + 2LL * 2048 * 512;  // 2 x [512][2048]
    unsigned short* pjw    = w2_t   + 2LL * 512 * 2048;
    unsigned short* P_bf   = pjw + 512LL * (96 + 192 + 384 + 768); // [3136][ch]
    unsigned short* pjw_i[4];
    const int chans[4] = {96, 192, 384, 768};
    {
        unsigned short* p = pjw;
        for (int i = 0; i < 4; ++i) { pjw_i[i] = p; p += 512LL * chans[i]; }
    }

    // ---- weight conversion ----
    wconv_t<<<dim3(1536/32, 512/32, 2), 256, 0, stream>>>(qkv_w, qkvw_t, 512, 1536);
    wconv_t<<<dim3(512/32, 512/32, 2), 256, 0, stream>>>(attn_pw, pw_t, 512, 512);
    wconv_t<<<dim3(2048/32, 512/32, 2), 256, 0, stream>>>(mlp_w1, w1_t, 512, 2048);
    wconv_t<<<dim3(512/32, 2048/32, 2), 256, 0, stream>>>(mlp_w2, w2_t, 2048, 512);
    for (int i = 0; i < 4; ++i) {
        int n = 512 * chans[i];
        wcv_k<<<(n + 255) / 256, 256, 0, stream>>>(proj_w[i], pjw_i[i], n);
    }

    // ---- pool + proj ----
    pool_k<8><<<64 * 96  / 4, 256, 0, stream>>>(feat[0], P_bf, 96);
    gemm_bf16<<<dim3(4, 25, 1), 256, 0, stream>>>(
        P_bf, 0, 96, pjw_i[0], 0, 96, X, 0, 512, proj_b[0], nullptr, 0,
        3136, 512, 96, 0, 1, 0, nullptr, nullptr, nullptr, 0.f);
    pool_k<4><<<64 * 192 / 4, 256, 0, stream>>>(feat[1], P_bf, 192);
    gemm_bf16<<<dim3(4, 25, 1), 256, 0, stream>>>(
        P_bf, 0, 192, pjw_i[1], 0, 192, X, 0, 512, proj_b[1], nullptr, 0,
        3136, 512, 192, 0, 1, 49, nullptr, nullptr, nullptr, 0.f);
    pool_k<2><<<64 * 384 / 4, 256, 0, stream>>>(feat[2], P_bf, 384);
    gemm_bf16<<<dim3(4, 25, 1), 256, 0, stream>>>(
        P_bf, 0, 384, pjw_i[2], 0, 384, X, 0, 512, proj_b[2], nullptr, 0,
        3136, 512, 384, 0, 1, 98, nullptr, nullptr, nullptr, 0.f);
    pool_k<1><<<64 * 768 / 4, 256, 0, stream>>>(feat[3], P_bf, 768);
    gemm_bf16<<<dim3(4, 25, 1), 256, 0, stream>>>(
        P_bf, 0, 768, pjw_i[3], 0, 768, X, 0, 512, proj_b[3], nullptr, 0,
        3136, 512, 768, 0, 1, 147, nullptr, nullptr, nullptr, 0.f);

    // ---- transformer layers ----
    for (int l = 0; l < 2; ++l) {
        // re-zero v_t + S_bf pads each layer: MLP hidden H aliases this region,
        // so layer-0's MLP clobbers the K-pad columns layer-1's PV reads.
        {
            long long n8 = (256LL * 224 * (128 + 196)) / 8;
            zero_k<<<(unsigned)((n8 + 255) / 256), 256, 0, stream>>>(v_t, n8);
        }

        ln_k<<<3136, 256, 0, stream>>>(X, XN_bf, ln1_g + l * 512, ln1_b + l * 512);

        gemm_bf16<<<dim3(12, 98, 1), 256, 0, stream>>>(
            XN_bf, 0, 512,
            qkvw_t + (long long)l * 1536 * 512, 0, 512,
            nullptr, 0, 0,
            qkv_b + l * 1536, nullptr, 0,
            12544, 1536, 512,
            0, 2, 0,
            q_bf, k_bf, v_t, 0.08838834764831845f);

        gemm_bf16<<<dim3(2, 2, 256), 256, 0, stream>>>(
            q_bf, 196LL * 128, 128,
            k_bf, 196LL * 128, 128,
            S, 196LL * 196, 196,
            nullptr, nullptr, 0,
            196, 196, 128,
            0, 0, 0,
            nullptr, nullptr, nullptr, 0.f);

        softmax_k<<<dim3(49, 256), 256, 0, stream>>>(S, S_bf, bias_table + (long long)l * 729 * 4);

        gemm_bf16<<<dim3(1, 2, 256), 256, 0, stream>>>(
            S_bf, 196LL * 224, 224,
            v_t, 128LL * 224, 224,
            O_bf, 0, 0,
            nullptr, nullptr, 0,
            196, 128, 224,
            0, 3, 0,
            nullptr, nullptr, nullptr, 0.f);

        gemm_bf16<<<dim3(4, 98, 1), 256, 0, stream>>>(
            O_bf, 0, 512,
            pw_t + (long long)l * 512 * 512, 0, 512,
            X, 0, 512,
            attn_pb + l * 512, X, 512,
            12544, 512, 512,
            0, 0, 0,
            nullptr, nullptr, nullptr, 0.f);

        ln_k<<<3136, 256, 0, stream>>>(X, XN_bf, ln2_g + l * 512, ln2_b + l * 512);

        gemm_bf16<<<dim3(16, 98, 1), 256, 0, stream>>>(
            XN_bf, 0, 512,
            w1_t + (long long)l * 2048 * 512, 0, 512,
            H, 0, 2048,
            mlp_b1 + l * 2048, nullptr, 0,
            12544, 2048, 512,
            1, 4, 0,
            nullptr, nullptr, nullptr, 0.f);

        gemm_bf16<<<dim3(4, 98, 1), 256, 0, stream>>>(
            H, 0, 2048,
            w2_t + (long long)l * 512 * 2048, 0, 2048,
            X, 0, 512,
            mlp_b2 + l * 512, X, 512,
            12544, 512, 2048,
            0, 0, 0,
            nullptr, nullptr, nullptr, 0.f);
    }

    mean_k<<<64, 512, 0, stream>>>(X, (float*)d_out);
}

// Round 7
// 885.778 us; speedup vs baseline: 5.6543x; 1.0053x over previous
//
#include <hip/hip_runtime.h>
#include <hip/hip_bf16.h>

typedef __attribute__((ext_vector_type(8))) short short8;
typedef __attribute__((ext_vector_type(4))) float f32x4;

__device__ __forceinline__ unsigned short f2bf(float x) {
    unsigned int u = __builtin_bit_cast(unsigned int, x);
    unsigned int r = (u + 0x7FFFu + ((u >> 16) & 1u)) >> 16;
    return (unsigned short)r;
}

__device__ __forceinline__ void gload_lds16(const unsigned short* g, unsigned short* l) {
    __builtin_amdgcn_global_load_lds(
        (const __attribute__((address_space(1))) unsigned int*)g,
        (__attribute__((address_space(3))) unsigned int*)l, 16, 0, 0);
}

// MFMA GEMM, all-bf16 operands: C = A[M,K] * B[N,K]^T + epilogue
// Ring-3 LDS, depth-2 prefetch, counted vmcnt (never 0 in loop), raw barriers.
// XOR swizzle both-sides (src col pre-permuted / read same XOR), LDS dest linear.
// mode 0: fp32 store C[r*ldc+n] (+res fp32, +relu)
// mode 1: proj row remap into X: orow=(r/49)*196+rowoff+r%49 (fp32)
// mode 2: qkv scatter -> q/k bf16 [z][196][128], v_t bf16 [z][128][224]
// mode 3: PV merge -> bf16 C[((z>>2)*196+r)*512 + (z&3)*128 + n]
// mode 4: bf16 store C[r*ldc+n] (+relu)
__global__ __launch_bounds__(256) void gemm_bf16(
    const unsigned short* __restrict__ A, long long sA, int lda,
    const unsigned short* __restrict__ B, long long sB, int ldb,
    void* __restrict__ Cv, long long sC, int ldc,
    const float* __restrict__ bias,
    const float* __restrict__ res, int ldres,
    int M, int N, int K,
    int relu, int mode, int rowoff,
    unsigned short* q_out, unsigned short* k_out, unsigned short* v_out,
    float qscale)
{
    const int z = blockIdx.z;
    A += (long long)z * sA;
    B += (long long)z * sB;

    const int bm = blockIdx.y * 128;
    const int bn = blockIdx.x * 128;

    __shared__ unsigned short As[3][128][32];
    __shared__ unsigned short Bs[3][128][32];

    const int tid  = threadIdx.x;
    const int lane = tid & 63;
    const int wid  = tid >> 6;
    const int wm   = wid >> 1;
    const int wn   = wid & 1;
    const int slot = lane >> 4;
    const int lcol = lane & 15;

    const int srow = tid >> 2;                           // 0..63 staging row
    const int sgrn = tid & 3;                            // LDS granule (linear)
    const int scol_dst = sgrn * 8;                       // LDS dest (linear tid*16B)
    const int scol_src = (sgrn ^ ((srow >> 1) & 3)) * 8; // swizzled global col

    // read-side swizzled granule: slot' = slot ^ ((row>>1)&3)
    const int rslot = (slot ^ ((lcol >> 1) & 3)) * 8;

    // clamped global rows (edge tiles read dup rows; epilogue guards)
    int ga0 = bm + srow;       if (ga0 > M - 1) ga0 = M - 1;
    int ga1 = bm + 64 + srow;  if (ga1 > M - 1) ga1 = M - 1;
    int gb0 = bn + srow;       if (gb0 > N - 1) gb0 = N - 1;
    int gb1 = bn + 64 + srow;  if (gb1 > N - 1) gb1 = N - 1;
    const unsigned short* pa0 = A + (long long)ga0 * lda + scol_src;
    const unsigned short* pa1 = A + (long long)ga1 * lda + scol_src;
    const unsigned short* pb0 = B + (long long)gb0 * ldb + scol_src;
    const unsigned short* pb1 = B + (long long)gb1 * ldb + scol_src;

    f32x4 acc[4][4];
    #pragma unroll
    for (int i = 0; i < 4; ++i)
        #pragma unroll
        for (int j = 0; j < 4; ++j)
            acc[i][j] = (f32x4){0.f, 0.f, 0.f, 0.f};

    const int nt = K >> 5;  // K/32 tiles (always >= 3 in this net)

    // prologue: stage tiles 0,1 into bufs 0,1 (8 VMEM ops in flight)
    gload_lds16(pa0, &As[0][srow][scol_dst]);
    gload_lds16(pa1, &As[0][64 + srow][scol_dst]);
    gload_lds16(pb0, &Bs[0][srow][scol_dst]);
    gload_lds16(pb1, &Bs[0][64 + srow][scol_dst]);
    if (nt > 1) {
        gload_lds16(pa0 + 32, &As[1][srow][scol_dst]);
        gload_lds16(pa1 + 32, &As[1][64 + srow][scol_dst]);
        gload_lds16(pb0 + 32, &Bs[1][srow][scol_dst]);
        gload_lds16(pb1 + 32, &Bs[1][64 + srow][scol_dst]);
    }

    int cur = 0;
    for (int t = 0; t < nt; ++t) {
        const int nxt2 = t + 2;
        if (nxt2 < nt) {
            const int nb = nxt2 % 3;
            const long long koff = (long long)nxt2 << 5;
            gload_lds16(pa0 + koff, &As[nb][srow][scol_dst]);
            gload_lds16(pa1 + koff, &As[nb][64 + srow][scol_dst]);
            gload_lds16(pb0 + koff, &Bs[nb][srow][scol_dst]);
            gload_lds16(pb1 + koff, &Bs[nb][64 + srow][scol_dst]);
        }
        // wait own tile-t loads: allow (tiles in flight after t) * 4 outstanding
        if (nxt2 < nt)          asm volatile("s_waitcnt vmcnt(8)" ::: "memory");
        else if (t + 1 < nt)    asm volatile("s_waitcnt vmcnt(4)" ::: "memory");
        else                    asm volatile("s_waitcnt vmcnt(0)" ::: "memory");
        __builtin_amdgcn_s_barrier();           // all waves' tile-t writes landed
        __builtin_amdgcn_sched_barrier(0);

        short8 afr[4], bfr[4];
        #pragma unroll
        for (int mi = 0; mi < 4; ++mi)
            afr[mi] = *(const short8*)&As[cur][wm * 64 + mi * 16 + lcol][rslot];
        #pragma unroll
        for (int ni = 0; ni < 4; ++ni)
            bfr[ni] = *(const short8*)&Bs[cur][wn * 64 + ni * 16 + lcol][rslot];
        #pragma unroll
        for (int mi = 0; mi < 4; ++mi)
            #pragma unroll
            for (int ni = 0; ni < 4; ++ni)
                acc[mi][ni] = __builtin_amdgcn_mfma_f32_16x16x32_bf16(
                    afr[mi], bfr[ni], acc[mi][ni], 0, 0, 0);

        __builtin_amdgcn_s_barrier();           // reads of buf[cur] done before reuse
        cur = (cur == 2) ? 0 : cur + 1;
    }

    // ---- epilogue ----
    float* Cf = (float*)Cv + (mode == 0 ? (long long)z * sC : 0);
    unsigned short* Cb = (unsigned short*)Cv;

    #pragma unroll
    for (int mi = 0; mi < 4; ++mi) {
        int rbase = bm + wm * 64 + mi * 16 + slot * 4;
        #pragma unroll
        for (int ni = 0; ni < 4; ++ni) {
            int gc = bn + wn * 64 + ni * 16 + lcol;
            if (gc >= N) continue;
            float bv = bias ? bias[gc] : 0.f;
            f32x4 a = acc[mi][ni];
            #pragma unroll
            for (int rr = 0; rr < 4; ++rr) {
                int gr = rbase + rr;
                if (gr >= M) continue;
                float v = a[rr] + bv;
                if (mode == 0) {
                    if (res) v += res[(long long)gr * ldres + gc];
                    if (relu) v = fmaxf(v, 0.f);
                    Cf[(long long)gr * ldc + gc] = v;
                } else if (mode == 1) {
                    int orow = (gr / 49) * 196 + rowoff + (gr % 49);
                    Cf[(long long)orow * ldc + gc] = v;
                } else if (mode == 2) {
                    int which = gc >> 9;
                    int hh = (gc >> 7) & 3;
                    int d  = gc & 127;
                    int b_ = gr / 196, l_ = gr % 196;
                    int zz = b_ * 4 + hh;
                    if (which == 0)
                        q_out[((long long)zz * 196 + l_) * 128 + d] = f2bf(v * qscale);
                    else if (which == 1)
                        k_out[((long long)zz * 196 + l_) * 128 + d] = f2bf(v);
                    else
                        v_out[((long long)zz * 128 + d) * 224 + l_] = f2bf(v);
                } else if (mode == 3) {
                    int bb = z >> 2, hh = z & 3;
                    Cb[((long long)(bb * 196 + gr)) * 512 + hh * 128 + gc] = f2bf(v);
                } else { // mode 4
                    if (relu) v = fmaxf(v, 0.f);
                    Cb[(long long)gr * ldc + gc] = f2bf(v);
                }
            }
        }
    }
}

// transpose+convert W[K][N] f32 -> Wt[N][K] bf16, layers via blockIdx.z
__global__ __launch_bounds__(256) void wconv_t(const float* __restrict__ W,
                                               unsigned short* __restrict__ Wt,
                                               int K, int N)
{
    W  += (long long)blockIdx.z * K * N;
    Wt += (long long)blockIdx.z * K * N;
    __shared__ float t[32][33];
    int tx = threadIdx.x & 31, ty = threadIdx.x >> 5;
    int n0 = blockIdx.x * 32, k0 = blockIdx.y * 32;
    #pragma unroll
    for (int j = 0; j < 4; ++j)
        t[ty + j * 8][tx] = W[(long long)(k0 + ty + j * 8) * N + n0 + tx];
    __syncthreads();
    #pragma unroll
    for (int j = 0; j < 4; ++j)
        Wt[(long long)(n0 + ty + j * 8) * K + k0 + tx] = f2bf(t[tx][ty + j * 8]);
}

__global__ __launch_bounds__(256) void wcv_k(const float* __restrict__ in,
                                             unsigned short* __restrict__ out, int n)
{
    int i = blockIdx.x * 256 + threadIdx.x;
    if (i < n) out[i] = f2bf(in[i]);
}

__global__ __launch_bounds__(256) void zero_k(unsigned short* __restrict__ p, long long n8)
{
    long long i = ((long long)blockIdx.x * 256 + threadIdx.x);
    if (i < n8) *(short8*)(p + i * 8) = (short8){0,0,0,0,0,0,0,0};
}

// adaptive avg-pool to 7x7 -> bf16 channels-last P[(b*49+t)*ch + c]
template<int F>
__global__ __launch_bounds__(256) void pool_k(const float* __restrict__ feat,
                                              unsigned short* __restrict__ P, int ch)
{
    const int S = 7 * F;
    int wv = blockIdx.x * 4 + (threadIdx.x >> 6);
    int lane = threadIdx.x & 63;
    int b = wv / ch, c = wv % ch;
    if (lane >= 49) return;
    int oh = lane / 7, ow = lane % 7;
    const float* src = feat + ((long long)b * ch + c) * (S * S) + (oh * F) * S + ow * F;
    float acc = 0.f;
    #pragma unroll
    for (int hh = 0; hh < F; ++hh) {
        const float* row = src + hh * S;
        if constexpr (F == 8) {
            float4 a = *(const float4*)row;
            float4 d = *(const float4*)(row + 4);
            acc += a.x + a.y + a.z + a.w + d.x + d.y + d.z + d.w;
        } else if constexpr (F == 4) {
            float4 a = *(const float4*)row;
            acc += a.x + a.y + a.z + a.w;
        } else if constexpr (F == 2) {
            float2 a = *(const float2*)row;
            acc += a.x + a.y;
        } else {
            acc += row[0];
        }
    }
    P[((long long)(b * 49 + lane)) * ch + c] = f2bf(acc * (1.f / (F * F)));
}

// LayerNorm over C=512 -> bf16 out; one wave per row, 4 rows/block
__global__ __launch_bounds__(256) void ln_k(const float* __restrict__ x,
                                            unsigned short* __restrict__ y,
                                            const float* __restrict__ g,
                                            const float* __restrict__ b)
{
    long long row = blockIdx.x * 4 + (threadIdx.x >> 6);
    const float* xr = x + row * 512;
    unsigned short* yr = y + row * 512;
    int lane = threadIdx.x & 63;
    float v[8];
    float s = 0.f, ss = 0.f;
    #pragma unroll
    for (int p = 0; p < 8; ++p) {
        v[p] = xr[lane + p * 64];
        s += v[p]; ss += v[p] * v[p];
    }
    #pragma unroll
    for (int off = 32; off >= 1; off >>= 1) {
        s  += __shfl_xor(s, off);
        ss += __shfl_xor(ss, off);
    }
    float mean = s * (1.f / 512.f);
    float var  = ss * (1.f / 512.f) - mean * mean;
    float rstd = rsqrtf(var + 1e-5f);
    #pragma unroll
    for (int p = 0; p < 8; ++p) {
        int c = lane + p * 64;
        yr[c] = f2bf((v[p] - mean) * rstd * g[c] + b[c]);
    }
}

// softmax over keys + relative bias; fp32 S in, bf16 Sb (ld 224) out.
__global__ __launch_bounds__(256) void softmax_k(const float* __restrict__ S,
                                                 unsigned short* __restrict__ Sb,
                                                 const float* __restrict__ bt)
{
    int zz = blockIdx.y;
    int l = blockIdx.x * 4 + (threadIdx.x >> 6);
    int lane = threadIdx.x & 63;
    int h = zz & 3;
    const float* row = S + ((long long)zz * 196 + l) * 196;
    unsigned short* orow = Sb + ((long long)zz * 196 + l) * 224;
    int i1 = l / 14, j1 = l % 14;

    float vals[4];
    float mx = -1e30f;
    #pragma unroll
    for (int p = 0; p < 4; ++p) {
        int m = lane + p * 64;
        float v = -1e30f;
        if (m < 196) {
            int i2 = m / 14, j2 = m % 14;
            int idx = (i1 - i2 + 13) * 27 + (j1 - j2 + 13);
            v = row[m] + bt[idx * 4 + h];
        }
        vals[p] = v;
        mx = fmaxf(mx, v);
    }
    #pragma unroll
    for (int off = 32; off >= 1; off >>= 1) mx = fmaxf(mx, __shfl_xor(mx, off));
    float sum = 0.f;
    #pragma unroll
    for (int p = 0; p < 4; ++p) {
        int m = lane + p * 64;
        float e = (m < 196) ? expf(vals[p] - mx) : 0.f;
        vals[p] = e; sum += e;
    }
    #pragma unroll
    for (int off = 32; off >= 1; off >>= 1) sum += __shfl_xor(sum, off);
    float inv = 1.f / sum;
    #pragma unroll
    for (int p = 0; p < 4; ++p) {
        int m = lane + p * 64;
        if (m < 196) orow[m] = f2bf(vals[p] * inv);
    }
}

__global__ __launch_bounds__(512) void mean_k(const float* __restrict__ X,
                                              float* __restrict__ out)
{
    int b = blockIdx.x, c = threadIdx.x;
    const float* xp = X + (long long)b * 196 * 512 + c;
    float s = 0.f;
    for (int t = 0; t < 196; ++t) s += xp[t * 512];
    out[b * 512 + c] = s * (1.f / 196.f);
}

extern "C" void kernel_launch(void* const* d_in, const int* in_sizes, int n_in,
                              void* d_out, int out_size, void* d_ws, size_t ws_size,
                              hipStream_t stream)
{
    const float* feat[4]   = {(const float*)d_in[0], (const float*)d_in[1],
                              (const float*)d_in[2], (const float*)d_in[3]};
    const float* proj_w[4] = {(const float*)d_in[4], (const float*)d_in[6],
                              (const float*)d_in[8], (const float*)d_in[10]};
    const float* proj_b[4] = {(const float*)d_in[5], (const float*)d_in[7],
                              (const float*)d_in[9], (const float*)d_in[11]};
    const float* ln1_g = (const float*)d_in[12];
    const float* ln1_b = (const float*)d_in[13];
    const float* qkv_w = (const float*)d_in[14];
    const float* qkv_b = (const float*)d_in[15];
    const float* bias_table = (const float*)d_in[16];
    const float* attn_pw = (const float*)d_in[17];
    const float* attn_pb = (const float*)d_in[18];
    const float* ln2_g = (const float*)d_in[19];
    const float* ln2_b = (const float*)d_in[20];
    const float* mlp_w1 = (const float*)d_in[21];
    const float* mlp_b1 = (const float*)d_in[22];
    const float* mlp_w2 = (const float*)d_in[23];
    const float* mlp_b2 = (const float*)d_in[24];

    const long long NXT = 64LL * 196 * 512;          // 6,422,528

    float* X  = (float*)d_ws;                        // [12544][512] f32
    float* S  = X + NXT;                             // [256][196][196] f32
    unsigned short* O_bf = (unsigned short*)S;       // PV out aliases S (dead then)

    unsigned short* ub    = (unsigned short*)(S + 256LL * 196 * 196);
    unsigned short* XN_bf = ub;                          // [12544][512]
    unsigned short* q_bf  = XN_bf + NXT;                 // [256][196][128]
    unsigned short* k_bf  = q_bf + NXT;                  // [256][196][128]
    unsigned short* v_t   = k_bf + NXT;                  // [256][128][224]
    unsigned short* S_bf  = v_t + 256LL * 128 * 224;     // [256][196][224]
    unsigned short* H     = q_bf;                        // MLP hidden aliases q..S_bf
    unsigned short* wts   = S_bf + 256LL * 196 * 224;

    unsigned short* qkvw_t = wts;                        // 2 x [1536][512]
    unsigned short* pw_t   = qkvw_t + 2LL * 1536 * 512;  // 2 x [512][512]
    unsigned short* w1_t   = pw_t   + 2LL * 512 * 512;   // 2 x [2048][512]
    unsigned short* w2_t   = w1_t   + 2LL * 2048 * 512;  // 2 x [512][2048]
    unsigned short* pjw    = w2_t   + 2LL * 512 * 2048;
    unsigned short* P_bf   = pjw + 512LL * (96 + 192 + 384 + 768); // [3136][ch]
    unsigned short* pjw_i[4];
    const int chans[4] = {96, 192, 384, 768};
    {
        unsigned short* p = pjw;
        for (int i = 0; i < 4; ++i) { pjw_i[i] = p; p += 512LL * chans[i]; }
    }

    // ---- weight conversion ----
    wconv_t<<<dim3(1536/32, 512/32, 2), 256, 0, stream>>>(qkv_w, qkvw_t, 512, 1536);
    wconv_t<<<dim3(512/32, 512/32, 2), 256, 0, stream>>>(attn_pw, pw_t, 512, 512);
    wconv_t<<<dim3(2048/32, 512/32, 2), 256, 0, stream>>>(mlp_w1, w1_t, 512, 2048);
    wconv_t<<<dim3(512/32, 2048/32, 2), 256, 0, stream>>>(mlp_w2, w2_t, 2048, 512);
    for (int i = 0; i < 4; ++i) {
        int n = 512 * chans[i];
        wcv_k<<<(n + 255) / 256, 256, 0, stream>>>(proj_w[i], pjw_i[i], n);
    }

    // ---- pool + proj ----
    pool_k<8><<<64 * 96  / 4, 256, 0, stream>>>(feat[0], P_bf, 96);
    gemm_bf16<<<dim3(4, 25, 1), 256, 0, stream>>>(
        P_bf, 0, 96, pjw_i[0], 0, 96, X, 0, 512, proj_b[0], nullptr, 0,
        3136, 512, 96, 0, 1, 0, nullptr, nullptr, nullptr, 0.f);
    pool_k<4><<<64 * 192 / 4, 256, 0, stream>>>(feat[1], P_bf, 192);
    gemm_bf16<<<dim3(4, 25, 1), 256, 0, stream>>>(
        P_bf, 0, 192, pjw_i[1], 0, 192, X, 0, 512, proj_b[1], nullptr, 0,
        3136, 512, 192, 0, 1, 49, nullptr, nullptr, nullptr, 0.f);
    pool_k<2><<<64 * 384 / 4, 256, 0, stream>>>(feat[2], P_bf, 384);
    gemm_bf16<<<dim3(4, 25, 1), 256, 0, stream>>>(
        P_bf, 0, 384, pjw_i[2], 0, 384, X, 0, 512, proj_b[2], nullptr, 0,
        3136, 512, 384, 0, 1, 98, nullptr, nullptr, nullptr, 0.f);
    pool_k<1><<<64 * 768 / 4, 256, 0, stream>>>(feat[3], P_bf, 768);
    gemm_bf16<<<dim3(4, 25, 1), 256, 0, stream>>>(
        P_bf, 0, 768, pjw_i[3], 0, 768, X, 0, 512, proj_b[3], nullptr, 0,
        3136, 512, 768, 0, 1, 147, nullptr, nullptr, nullptr, 0.f);

    // ---- transformer layers ----
    for (int l = 0; l < 2; ++l) {
        // re-zero v_t + S_bf pads each layer: MLP hidden H aliases this region,
        // so layer-0's MLP clobbers the K-pad columns layer-1's PV reads.
        {
            long long n8 = (256LL * 224 * (128 + 196)) / 8;
            zero_k<<<(unsigned)((n8 + 255) / 256), 256, 0, stream>>>(v_t, n8);
        }

        ln_k<<<3136, 256, 0, stream>>>(X, XN_bf, ln1_g + l * 512, ln1_b + l * 512);

        gemm_bf16<<<dim3(12, 98, 1), 256, 0, stream>>>(
            XN_bf, 0, 512,
            qkvw_t + (long long)l * 1536 * 512, 0, 512,
            nullptr, 0, 0,
            qkv_b + l * 1536, nullptr, 0,
            12544, 1536, 512,
            0, 2, 0,
            q_bf, k_bf, v_t, 0.08838834764831845f);

        gemm_bf16<<<dim3(2, 2, 256), 256, 0, stream>>>(
            q_bf, 196LL * 128, 128,
            k_bf, 196LL * 128, 128,
            S, 196LL * 196, 196,
            nullptr, nullptr, 0,
            196, 196, 128,
            0, 0, 0,
            nullptr, nullptr, nullptr, 0.f);

        softmax_k<<<dim3(49, 256), 256, 0, stream>>>(S, S_bf, bias_table + (long long)l * 729 * 4);

        gemm_bf16<<<dim3(1, 2, 256), 256, 0, stream>>>(
            S_bf, 196LL * 224, 224,
            v_t, 128LL * 224, 224,
            O_bf, 0, 0,
            nullptr, nullptr, 0,
            196, 128, 224,
            0, 3, 0,
            nullptr, nullptr, nullptr, 0.f);

        gemm_bf16<<<dim3(4, 98, 1), 256, 0, stream>>>(
            O_bf, 0, 512,
            pw_t + (long long)l * 512 * 512, 0, 512,
            X, 0, 512,
            attn_pb + l * 512, X, 512,
            12544, 512, 512,
            0, 0, 0,
            nullptr, nullptr, nullptr, 0.f);

        ln_k<<<3136, 256, 0, stream>>>(X, XN_bf, ln2_g + l * 512, ln2_b + l * 512);

        gemm_bf16<<<dim3(16, 98, 1), 256, 0, stream>>>(
            XN_bf, 0, 512,
            w1_t + (long long)l * 2048 * 512, 0, 512,
            H, 0, 2048,
            mlp_b1 + l * 2048, nullptr, 0,
            12544, 2048, 512,
            1, 4, 0,
            nullptr, nullptr, nullptr, 0.f);

        gemm_bf16<<<dim3(4, 98, 1), 256, 0, stream>>>(
            H, 0, 2048,
            w2_t + (long long)l * 512 * 2048, 0, 2048,
            X, 0, 512,
            mlp_b2 + l * 512, X, 512,
            12544, 512, 2048,
            0, 0, 0,
            nullptr, nullptr, nullptr, 0.f);
    }

    mean_k<<<64, 512, 0, stream>>>(X, (float*)d_out);
}

// Round 8
// 858.442 us; speedup vs baseline: 5.8344x; 1.0318x over previous
//
#include <hip/hip_runtime.h>
#include <hip/hip_bf16.h>

typedef __attribute__((ext_vector_type(8))) short short8;
typedef __attribute__((ext_vector_type(4))) float f32x4;

__device__ __forceinline__ unsigned short f2bf(float x) {
    unsigned int u = __builtin_bit_cast(unsigned int, x);
    unsigned int r = (u + 0x7FFFu + ((u >> 16) & 1u)) >> 16;
    return (unsigned short)r;
}

__device__ __forceinline__ void gload_lds16(const unsigned short* g, unsigned short* l) {
    __builtin_amdgcn_global_load_lds(
        (const __attribute__((address_space(1))) unsigned int*)g,
        (__attribute__((address_space(3))) unsigned int*)l, 16, 0, 0);
}

// ---------------- GEMM (unchanged round-7 structure) ----------------
// MFMA GEMM, all-bf16 operands: C = A[M,K] * B[N,K]^T + epilogue
// Ring-3 LDS, depth-2 prefetch, counted vmcnt, XOR swizzle both-sides.
// mode 0: fp32 store (+res fp32, +relu)
// mode 1: proj row remap (fp32)
// mode 2: qkv scatter -> q/k bf16 [z][196][128], v_t bf16 [z][128][224]
// mode 4: bf16 store (+relu)
__global__ __launch_bounds__(256) void gemm_bf16(
    const unsigned short* __restrict__ A, long long sA, int lda,
    const unsigned short* __restrict__ B, long long sB, int ldb,
    void* __restrict__ Cv, long long sC, int ldc,
    const float* __restrict__ bias,
    const float* __restrict__ res, int ldres,
    int M, int N, int K,
    int relu, int mode, int rowoff,
    unsigned short* q_out, unsigned short* k_out, unsigned short* v_out,
    float qscale)
{
    const int z = blockIdx.z;
    A += (long long)z * sA;
    B += (long long)z * sB;

    const int bm = blockIdx.y * 128;
    const int bn = blockIdx.x * 128;

    __shared__ unsigned short As[3][128][32];
    __shared__ unsigned short Bs[3][128][32];

    const int tid  = threadIdx.x;
    const int lane = tid & 63;
    const int wid  = tid >> 6;
    const int wm   = wid >> 1;
    const int wn   = wid & 1;
    const int slot = lane >> 4;
    const int lcol = lane & 15;

    const int srow = tid >> 2;
    const int sgrn = tid & 3;
    const int scol_dst = sgrn * 8;
    const int scol_src = (sgrn ^ ((srow >> 1) & 3)) * 8;
    const int rslot = (slot ^ ((lcol >> 1) & 3)) * 8;

    int ga0 = bm + srow;       if (ga0 > M - 1) ga0 = M - 1;
    int ga1 = bm + 64 + srow;  if (ga1 > M - 1) ga1 = M - 1;
    int gb0 = bn + srow;       if (gb0 > N - 1) gb0 = N - 1;
    int gb1 = bn + 64 + srow;  if (gb1 > N - 1) gb1 = N - 1;
    const unsigned short* pa0 = A + (long long)ga0 * lda + scol_src;
    const unsigned short* pa1 = A + (long long)ga1 * lda + scol_src;
    const unsigned short* pb0 = B + (long long)gb0 * ldb + scol_src;
    const unsigned short* pb1 = B + (long long)gb1 * ldb + scol_src;

    f32x4 acc[4][4];
    #pragma unroll
    for (int i = 0; i < 4; ++i)
        #pragma unroll
        for (int j = 0; j < 4; ++j)
            acc[i][j] = (f32x4){0.f, 0.f, 0.f, 0.f};

    const int nt = K >> 5;

    gload_lds16(pa0, &As[0][srow][scol_dst]);
    gload_lds16(pa1, &As[0][64 + srow][scol_dst]);
    gload_lds16(pb0, &Bs[0][srow][scol_dst]);
    gload_lds16(pb1, &Bs[0][64 + srow][scol_dst]);
    if (nt > 1) {
        gload_lds16(pa0 + 32, &As[1][srow][scol_dst]);
        gload_lds16(pa1 + 32, &As[1][64 + srow][scol_dst]);
        gload_lds16(pb0 + 32, &Bs[1][srow][scol_dst]);
        gload_lds16(pb1 + 32, &Bs[1][64 + srow][scol_dst]);
    }

    int cur = 0;
    for (int t = 0; t < nt; ++t) {
        const int nxt2 = t + 2;
        if (nxt2 < nt) {
            const int nb = nxt2 % 3;
            const long long koff = (long long)nxt2 << 5;
            gload_lds16(pa0 + koff, &As[nb][srow][scol_dst]);
            gload_lds16(pa1 + koff, &As[nb][64 + srow][scol_dst]);
            gload_lds16(pb0 + koff, &Bs[nb][srow][scol_dst]);
            gload_lds16(pb1 + koff, &Bs[nb][64 + srow][scol_dst]);
        }
        if (nxt2 < nt)          asm volatile("s_waitcnt vmcnt(8)" ::: "memory");
        else if (t + 1 < nt)    asm volatile("s_waitcnt vmcnt(4)" ::: "memory");
        else                    asm volatile("s_waitcnt vmcnt(0)" ::: "memory");
        __builtin_amdgcn_s_barrier();
        __builtin_amdgcn_sched_barrier(0);

        short8 afr[4], bfr[4];
        #pragma unroll
        for (int mi = 0; mi < 4; ++mi)
            afr[mi] = *(const short8*)&As[cur][wm * 64 + mi * 16 + lcol][rslot];
        #pragma unroll
        for (int ni = 0; ni < 4; ++ni)
            bfr[ni] = *(const short8*)&Bs[cur][wn * 64 + ni * 16 + lcol][rslot];
        #pragma unroll
        for (int mi = 0; mi < 4; ++mi)
            #pragma unroll
            for (int ni = 0; ni < 4; ++ni)
                acc[mi][ni] = __builtin_amdgcn_mfma_f32_16x16x32_bf16(
                    afr[mi], bfr[ni], acc[mi][ni], 0, 0, 0);

        __builtin_amdgcn_s_barrier();
        cur = (cur == 2) ? 0 : cur + 1;
    }

    float* Cf = (float*)Cv + (mode == 0 ? (long long)z * sC : 0);
    unsigned short* Cb = (unsigned short*)Cv;

    #pragma unroll
    for (int mi = 0; mi < 4; ++mi) {
        int rbase = bm + wm * 64 + mi * 16 + slot * 4;
        #pragma unroll
        for (int ni = 0; ni < 4; ++ni) {
            int gc = bn + wn * 64 + ni * 16 + lcol;
            if (gc >= N) continue;
            float bv = bias ? bias[gc] : 0.f;
            f32x4 a = acc[mi][ni];
            #pragma unroll
            for (int rr = 0; rr < 4; ++rr) {
                int gr = rbase + rr;
                if (gr >= M) continue;
                float v = a[rr] + bv;
                if (mode == 0) {
                    if (res) v += res[(long long)gr * ldres + gc];
                    if (relu) v = fmaxf(v, 0.f);
                    Cf[(long long)gr * ldc + gc] = v;
                } else if (mode == 1) {
                    int orow = (gr / 49) * 196 + rowoff + (gr % 49);
                    Cf[(long long)orow * ldc + gc] = v;
                } else if (mode == 2) {
                    int which = gc >> 9;
                    int hh = (gc >> 7) & 3;
                    int d  = gc & 127;
                    int b_ = gr / 196, l_ = gr % 196;
                    int zz = b_ * 4 + hh;
                    if (which == 0)
                        q_out[((long long)zz * 196 + l_) * 128 + d] = f2bf(v * qscale);
                    else if (which == 1)
                        k_out[((long long)zz * 196 + l_) * 128 + d] = f2bf(v);
                    else
                        v_out[((long long)zz * 128 + d) * 224 + l_] = f2bf(v);
                } else { // mode 4
                    if (relu) v = fmaxf(v, 0.f);
                    Cb[(long long)gr * ldc + gc] = f2bf(v);
                }
            }
        }
    }
}

// ---------------- fused flash attention ----------------
// One block per (b,h)=z. 4 waves, each owns 4 query row-tiles {w,w+4,w+8,w+12}
// (rows padded to 256; pad rows never written). No __syncthreads: Ps is
// per-wave. Q-frags hoisted to regs; K/V frags direct 16B global loads
// (L2-resident). v_t pads (keys>=196) are masked: P=0 kills garbage.
__global__ __launch_bounds__(256) void flash_k(
    const unsigned short* __restrict__ q_bf,   // [256][196][128] (pre-scaled)
    const unsigned short* __restrict__ k_bf,   // [256][196][128]
    const unsigned short* __restrict__ v_t,    // [256][128][224] (V^T, d-major)
    unsigned short* __restrict__ O,            // [12544][512]
    const float* __restrict__ bt)              // [729][4] for this layer
{
    const int z = blockIdx.x;
    const int h = z & 3, bb = z >> 2;
    const int tid = threadIdx.x;
    const int w = tid >> 6;
    const int lane = tid & 63;
    const int slot = lane >> 4;
    const int lcol = lane & 15;

    __shared__ unsigned short Ps[4][16][68];   // per-wave P relayout, 2-way banks

    const unsigned short* Qz = q_bf + (long long)z * 196 * 128;
    const unsigned short* Kz = k_bf + (long long)z * 196 * 128;
    const unsigned short* Vz = v_t  + (long long)z * 128 * 224;

    // Q fragments: rows (w+4i)*16+lcol, d-slices ks*32+slot*8
    short8 qf[4][4];
    #pragma unroll
    for (int i = 0; i < 4; ++i) {
        const int row = (w + 4 * i) * 16 + lcol;
        #pragma unroll
        for (int ks = 0; ks < 4; ++ks)
            qf[i][ks] = *(const short8*)(Qz + (long long)row * 128 + ks * 32 + slot * 8);
    }

    f32x4 o[4][8];
    #pragma unroll
    for (int i = 0; i < 4; ++i)
        #pragma unroll
        for (int nd = 0; nd < 8; ++nd)
            o[i][nd] = (f32x4){0.f, 0.f, 0.f, 0.f};

    float m_r[4][4], l_r[4][4];
    #pragma unroll
    for (int i = 0; i < 4; ++i)
        #pragma unroll
        for (int r = 0; r < 4; ++r) { m_r[i][r] = -3e38f; l_r[i][r] = 0.f; }

    // per-row bias coords (clamped for pad rows)
    int qi1[4][4], qj1[4][4];
    #pragma unroll
    for (int i = 0; i < 4; ++i)
        #pragma unroll
        for (int r = 0; r < 4; ++r) {
            int q = (w + 4 * i) * 16 + slot * 4 + r;
            int qq = q < 195 ? q : 195;
            qi1[i][r] = qq / 14;
            qj1[i][r] = qq % 14;
        }

    #pragma unroll
    for (int kt = 0; kt < 4; ++kt) {
        const int nkj  = (kt == 3) ? 2 : 4;   // kt3: keys 192..223 (ksl0 span)
        const int nksl = (kt == 3) ? 1 : 2;

        // K fragments (keys = kt*64+kj*16+lcol, d-slices)
        short8 kf[4][4];
        #pragma unroll
        for (int kj = 0; kj < 4; ++kj) {
            if (kj >= nkj) continue;
            const int krow = kt * 64 + kj * 16 + lcol;
            #pragma unroll
            for (int ks = 0; ks < 4; ++ks)
                kf[kj][ks] = *(const short8*)(Kz + (long long)krow * 128 + ks * 32 + slot * 8);
        }

        // S = Q K^T
        f32x4 s[4][4];
        #pragma unroll
        for (int i = 0; i < 4; ++i)
            #pragma unroll
            for (int kj = 0; kj < 4; ++kj) {
                if (kj >= nkj) continue;
                f32x4 a = (f32x4){0.f, 0.f, 0.f, 0.f};
                #pragma unroll
                for (int ks = 0; ks < 4; ++ks)
                    a = __builtin_amdgcn_mfma_f32_16x16x32_bf16(qf[i][ks], kf[kj][ks], a, 0, 0, 0);
                s[i][kj] = a;
            }

        // V fragments (d = nd*16+lcol, key-slices)
        short8 vf[8][2];
        #pragma unroll
        for (int nd = 0; nd < 8; ++nd)
            #pragma unroll
            for (int ksl = 0; ksl < 2; ++ksl) {
                if (ksl >= nksl) continue;
                vf[nd][ksl] = *(const short8*)(Vz + (long long)(nd * 16 + lcol) * 224
                                               + kt * 64 + ksl * 32 + slot * 8);
            }

        #pragma unroll
        for (int i = 0; i < 4; ++i) {
            // bias + key mask
            #pragma unroll
            for (int kj = 0; kj < 4; ++kj) {
                if (kj >= nkj) continue;
                const int key = kt * 64 + kj * 16 + lcol;
                const int kk = key < 195 ? key : 195;
                const int i2 = kk / 14, j2 = kk % 14;
                #pragma unroll
                for (int r = 0; r < 4; ++r) {
                    const int idx = (qi1[i][r] - i2 + 13) * 27 + (qj1[i][r] - j2 + 13);
                    float sv = s[i][kj][r] + bt[idx * 4 + h];
                    if (key >= 196) sv = -3e38f;
                    s[i][kj][r] = sv;
                }
            }
            // row max over kj + 16 lcol lanes
            f32x4 pm = s[i][0];
            #pragma unroll
            for (int kj = 1; kj < 4; ++kj) {
                if (kj >= nkj) continue;
                #pragma unroll
                for (int r = 0; r < 4; ++r) pm[r] = fmaxf(pm[r], s[i][kj][r]);
            }
            #pragma unroll
            for (int r = 0; r < 4; ++r) {
                #pragma unroll
                for (int off = 1; off < 16; off <<= 1)
                    pm[r] = fmaxf(pm[r], __shfl_xor(pm[r], off));
            }
            float sf[4];
            #pragma unroll
            for (int r = 0; r < 4; ++r) {
                float mn = fmaxf(m_r[i][r], pm[r]);
                sf[r] = __expf(m_r[i][r] - mn);
                m_r[i][r] = mn;
            }
            // P = exp(S - m), l update
            f32x4 ladd = (f32x4){0.f, 0.f, 0.f, 0.f};
            #pragma unroll
            for (int kj = 0; kj < 4; ++kj) {
                if (kj >= nkj) continue;
                #pragma unroll
                for (int r = 0; r < 4; ++r) {
                    float p = __expf(s[i][kj][r] - m_r[i][r]);
                    s[i][kj][r] = p;
                    ladd[r] += p;
                }
            }
            #pragma unroll
            for (int r = 0; r < 4; ++r) {
                #pragma unroll
                for (int off = 1; off < 16; off <<= 1)
                    ladd[r] += __shfl_xor(ladd[r], off);
                l_r[i][r] = l_r[i][r] * sf[r] + ladd[r];
            }
            // rescale O
            #pragma unroll
            for (int nd = 0; nd < 8; ++nd)
                #pragma unroll
                for (int r = 0; r < 4; ++r) o[i][nd][r] *= sf[r];
            // P -> LDS (bf16), per-wave region
            #pragma unroll
            for (int kj = 0; kj < 4; ++kj) {
                if (kj >= nkj) continue;
                #pragma unroll
                for (int r = 0; r < 4; ++r)
                    Ps[w][slot * 4 + r][kj * 16 + lcol] = f2bf(s[i][kj][r]);
            }
            // PV
            #pragma unroll
            for (int ksl = 0; ksl < 2; ++ksl) {
                if (ksl >= nksl) continue;
                short8 pa = *(const short8*)&Ps[w][lcol][ksl * 32 + slot * 8];
                #pragma unroll
                for (int nd = 0; nd < 8; ++nd)
                    o[i][nd] = __builtin_amdgcn_mfma_f32_16x16x32_bf16(pa, vf[nd][ksl], o[i][nd], 0, 0, 0);
            }
        }
    }

    // write O (bf16), skip pad rows
    #pragma unroll
    for (int i = 0; i < 4; ++i) {
        #pragma unroll
        for (int r = 0; r < 4; ++r) {
            const int q = (w + 4 * i) * 16 + slot * 4 + r;
            if (q >= 196) continue;
            const float rn = 1.f / l_r[i][r];
            unsigned short* op = O + ((long long)(bb * 196 + q)) * 512 + h * 128 + lcol;
            #pragma unroll
            for (int nd = 0; nd < 8; ++nd)
                op[nd * 16] = f2bf(o[i][nd][r] * rn);
        }
    }
}

// transpose+convert W[K][N] f32 -> Wt[N][K] bf16, layers via blockIdx.z
__global__ __launch_bounds__(256) void wconv_t(const float* __restrict__ W,
                                               unsigned short* __restrict__ Wt,
                                               int K, int N)
{
    W  += (long long)blockIdx.z * K * N;
    Wt += (long long)blockIdx.z * K * N;
    __shared__ float t[32][33];
    int tx = threadIdx.x & 31, ty = threadIdx.x >> 5;
    int n0 = blockIdx.x * 32, k0 = blockIdx.y * 32;
    #pragma unroll
    for (int j = 0; j < 4; ++j)
        t[ty + j * 8][tx] = W[(long long)(k0 + ty + j * 8) * N + n0 + tx];
    __syncthreads();
    #pragma unroll
    for (int j = 0; j < 4; ++j)
        Wt[(long long)(n0 + ty + j * 8) * K + k0 + tx] = f2bf(t[tx][ty + j * 8]);
}

__global__ __launch_bounds__(256) void wcv_k(const float* __restrict__ in,
                                             unsigned short* __restrict__ out, int n)
{
    int i = blockIdx.x * 256 + threadIdx.x;
    if (i < n) out[i] = f2bf(in[i]);
}

// adaptive avg-pool to 7x7 -> bf16 channels-last P[(b*49+t)*ch + c]
template<int F>
__global__ __launch_bounds__(256) void pool_k(const float* __restrict__ feat,
                                              unsigned short* __restrict__ P, int ch)
{
    const int S = 7 * F;
    int wv = blockIdx.x * 4 + (threadIdx.x >> 6);
    int lane = threadIdx.x & 63;
    int b = wv / ch, c = wv % ch;
    if (lane >= 49) return;
    int oh = lane / 7, ow = lane % 7;
    const float* src = feat + ((long long)b * ch + c) * (S * S) + (oh * F) * S + ow * F;
    float acc = 0.f;
    #pragma unroll
    for (int hh = 0; hh < F; ++hh) {
        const float* row = src + hh * S;
        if constexpr (F == 8) {
            float4 a = *(const float4*)row;
            float4 d = *(const float4*)(row + 4);
            acc += a.x + a.y + a.z + a.w + d.x + d.y + d.z + d.w;
        } else if constexpr (F == 4) {
            float4 a = *(const float4*)row;
            acc += a.x + a.y + a.z + a.w;
        } else if constexpr (F == 2) {
            float2 a = *(const float2*)row;
            acc += a.x + a.y;
        } else {
            acc += row[0];
        }
    }
    P[((long long)(b * 49 + lane)) * ch + c] = f2bf(acc * (1.f / (F * F)));
}

// LayerNorm over C=512 -> bf16 out; one wave per row, 4 rows/block
__global__ __launch_bounds__(256) void ln_k(const float* __restrict__ x,
                                            unsigned short* __restrict__ y,
                                            const float* __restrict__ g,
                                            const float* __restrict__ b)
{
    long long row = blockIdx.x * 4 + (threadIdx.x >> 6);
    const float* xr = x + row * 512;
    unsigned short* yr = y + row * 512;
    int lane = threadIdx.x & 63;
    float v[8];
    float s = 0.f, ss = 0.f;
    #pragma unroll
    for (int p = 0; p < 8; ++p) {
        v[p] = xr[lane + p * 64];
        s += v[p]; ss += v[p] * v[p];
    }
    #pragma unroll
    for (int off = 32; off >= 1; off >>= 1) {
        s  += __shfl_xor(s, off);
        ss += __shfl_xor(ss, off);
    }
    float mean = s * (1.f / 512.f);
    float var  = ss * (1.f / 512.f) - mean * mean;
    float rstd = rsqrtf(var + 1e-5f);
    #pragma unroll
    for (int p = 0; p < 8; ++p) {
        int c = lane + p * 64;
        yr[c] = f2bf((v[p] - mean) * rstd * g[c] + b[c]);
    }
}

__global__ __launch_bounds__(512) void mean_k(const float* __restrict__ X,
                                              float* __restrict__ out)
{
    int b = blockIdx.x, c = threadIdx.x;
    const float* xp = X + (long long)b * 196 * 512 + c;
    float s = 0.f;
    for (int t = 0; t < 196; ++t) s += xp[t * 512];
    out[b * 512 + c] = s * (1.f / 196.f);
}

extern "C" void kernel_launch(void* const* d_in, const int* in_sizes, int n_in,
                              void* d_out, int out_size, void* d_ws, size_t ws_size,
                              hipStream_t stream)
{
    const float* feat[4]   = {(const float*)d_in[0], (const float*)d_in[1],
                              (const float*)d_in[2], (const float*)d_in[3]};
    const float* proj_w[4] = {(const float*)d_in[4], (const float*)d_in[6],
                              (const float*)d_in[8], (const float*)d_in[10]};
    const float* proj_b[4] = {(const float*)d_in[5], (const float*)d_in[7],
                              (const float*)d_in[9], (const float*)d_in[11]};
    const float* ln1_g = (const float*)d_in[12];
    const float* ln1_b = (const float*)d_in[13];
    const float* qkv_w = (const float*)d_in[14];
    const float* qkv_b = (const float*)d_in[15];
    const float* bias_table = (const float*)d_in[16];
    const float* attn_pw = (const float*)d_in[17];
    const float* attn_pb = (const float*)d_in[18];
    const float* ln2_g = (const float*)d_in[19];
    const float* ln2_b = (const float*)d_in[20];
    const float* mlp_w1 = (const float*)d_in[21];
    const float* mlp_b1 = (const float*)d_in[22];
    const float* mlp_w2 = (const float*)d_in[23];
    const float* mlp_b2 = (const float*)d_in[24];

    const long long NXT = 64LL * 196 * 512;          // 6,422,528

    float* X  = (float*)d_ws;                        // [12544][512] f32
    float* S  = X + NXT;                             // scratch region
    unsigned short* O_bf = (unsigned short*)S;       // attention out [12544][512] bf16

    unsigned short* ub    = (unsigned short*)(S + 256LL * 196 * 196);
    unsigned short* XN_bf = ub;                          // [12544][512]
    unsigned short* q_bf  = XN_bf + NXT;                 // [256][196][128]
    unsigned short* k_bf  = q_bf + NXT;                  // [256][196][128]
    unsigned short* v_t   = k_bf + NXT;                  // [256][128][224]
    unsigned short* H     = q_bf;                        // MLP hidden aliases q..v_t
    unsigned short* wts   = v_t + 256LL * 128 * 224 + 256LL * 196 * 224;

    unsigned short* qkvw_t = wts;                        // 2 x [1536][512]
    unsigned short* pw_t   = qkvw_t + 2LL * 1536 * 512;  // 2 x [512][512]
    unsigned short* w1_t   = pw_t   + 2LL * 512 * 512;   // 2 x [2048][512]
    unsigned short* w2_t   = w1_t   + 2LL * 2048 * 512;  // 2 x [512][2048]
    unsigned short* pjw    = w2_t   + 2LL * 512 * 2048;
    unsigned short* P_bf   = pjw + 512LL * (96 + 192 + 384 + 768); // [3136][ch]
    unsigned short* pjw_i[4];
    const int chans[4] = {96, 192, 384, 768};
    {
        unsigned short* p = pjw;
        for (int i = 0; i < 4; ++i) { pjw_i[i] = p; p += 512LL * chans[i]; }
    }

    // ---- weight conversion ----
    wconv_t<<<dim3(1536/32, 512/32, 2), 256, 0, stream>>>(qkv_w, qkvw_t, 512, 1536);
    wconv_t<<<dim3(512/32, 512/32, 2), 256, 0, stream>>>(attn_pw, pw_t, 512, 512);
    wconv_t<<<dim3(2048/32, 512/32, 2), 256, 0, stream>>>(mlp_w1, w1_t, 512, 2048);
    wconv_t<<<dim3(512/32, 2048/32, 2), 256, 0, stream>>>(mlp_w2, w2_t, 2048, 512);
    for (int i = 0; i < 4; ++i) {
        int n = 512 * chans[i];
        wcv_k<<<(n + 255) / 256, 256, 0, stream>>>(proj_w[i], pjw_i[i], n);
    }

    // ---- pool + proj ----
    pool_k<8><<<64 * 96  / 4, 256, 0, stream>>>(feat[0], P_bf, 96);
    gemm_bf16<<<dim3(4, 25, 1), 256, 0, stream>>>(
        P_bf, 0, 96, pjw_i[0], 0, 96, X, 0, 512, proj_b[0], nullptr, 0,
        3136, 512, 96, 0, 1, 0, nullptr, nullptr, nullptr, 0.f);
    pool_k<4><<<64 * 192 / 4, 256, 0, stream>>>(feat[1], P_bf, 192);
    gemm_bf16<<<dim3(4, 25, 1), 256, 0, stream>>>(
        P_bf, 0, 192, pjw_i[1], 0, 192, X, 0, 512, proj_b[1], nullptr, 0,
        3136, 512, 192, 0, 1, 49, nullptr, nullptr, nullptr, 0.f);
    pool_k<2><<<64 * 384 / 4, 256, 0, stream>>>(feat[2], P_bf, 384);
    gemm_bf16<<<dim3(4, 25, 1), 256, 0, stream>>>(
        P_bf, 0, 384, pjw_i[2], 0, 384, X, 0, 512, proj_b[2], nullptr, 0,
        3136, 512, 384, 0, 1, 98, nullptr, nullptr, nullptr, 0.f);
    pool_k<1><<<64 * 768 / 4, 256, 0, stream>>>(feat[3], P_bf, 768);
    gemm_bf16<<<dim3(4, 25, 1), 256, 0, stream>>>(
        P_bf, 0, 768, pjw_i[3], 0, 768, X, 0, 512, proj_b[3], nullptr, 0,
        3136, 512, 768, 0, 1, 147, nullptr, nullptr, nullptr, 0.f);

    // ---- transformer layers ----
    for (int l = 0; l < 2; ++l) {
        ln_k<<<3136, 256, 0, stream>>>(X, XN_bf, ln1_g + l * 512, ln1_b + l * 512);

        gemm_bf16<<<dim3(12, 98, 1), 256, 0, stream>>>(
            XN_bf, 0, 512,
            qkvw_t + (long long)l * 1536 * 512, 0, 512,
            nullptr, 0, 0,
            qkv_b + l * 1536, nullptr, 0,
            12544, 1536, 512,
            0, 2, 0,
            q_bf, k_bf, v_t, 0.08838834764831845f);

        // fused attention: QK^T + bias + softmax + PV -> O_bf
        flash_k<<<256, 256, 0, stream>>>(q_bf, k_bf, v_t, O_bf,
                                         bias_table + (long long)l * 729 * 4);

        gemm_bf16<<<dim3(4, 98, 1), 256, 0, stream>>>(
            O_bf, 0, 512,
            pw_t + (long long)l * 512 * 512, 0, 512,
            X, 0, 512,
            attn_pb + l * 512, X, 512,
            12544, 512, 512,
            0, 0, 0,
            nullptr, nullptr, nullptr, 0.f);

        ln_k<<<3136, 256, 0, stream>>>(X, XN_bf, ln2_g + l * 512, ln2_b + l * 512);

        gemm_bf16<<<dim3(16, 98, 1), 256, 0, stream>>>(
            XN_bf, 0, 512,
            w1_t + (long long)l * 2048 * 512, 0, 512,
            H, 0, 2048,
            mlp_b1 + l * 2048, nullptr, 0,
            12544, 2048, 512,
            1, 4, 0,
            nullptr, nullptr, nullptr, 0.f);

        gemm_bf16<<<dim3(4, 98, 1), 256, 0, stream>>>(
            H, 0, 2048,
            w2_t + (long long)l * 512 * 2048, 0, 2048,
            X, 0, 512,
            mlp_b2 + l * 512, X, 512,
            12544, 512, 2048,
            0, 0, 0,
            nullptr, nullptr, nullptr, 0.f);
    }

    mean_k<<<64, 512, 0, stream>>>(X, (float*)d_out);
}